// Round 11
// baseline (292.348 us; speedup 1.0000x reference)
//
#include <hip/hip_runtime.h>
#include <stdint.h>

// MambaEncoder on MI355X (gfx950).
// ALL inputs and the output are FLOAT32. Intermediates bf16 in workspace,
// TIME-MAJOR; dbc n-major. Weights prepacked fp32->bf16. Step-2 GEMM
// (the 8.6 GF bulk) uses BK=64 + register double-buffering so global-load
// latency hides behind 32 MFMAs per barrier pair (R10: 2-barrier BK=32
// K-loop at KT=8 ran ~100 TF). CTRANS epilogues via LDS transpose.
// Scan: single-pass chunked associative scan, 8 states/thread.

typedef unsigned short u16;
typedef __bf16 bf16x8 __attribute__((ext_vector_type(8)));
typedef float f32x4 __attribute__((ext_vector_type(4)));

#define LOG2E 1.44269504088896f

__device__ __forceinline__ float b2f(u16 h) {
    union { unsigned int u; float f; } c; c.u = ((unsigned int)h) << 16; return c.f;
}
__device__ __forceinline__ u16 f2b(float f) {   // round-to-nearest-even
    union { float f; unsigned int u; } c; c.f = f;
    unsigned int r = c.u + 0x7FFFu + ((c.u >> 16) & 1u);
    return (u16)(r >> 16);
}
__device__ __forceinline__ void unpk2(unsigned int u, float& lo, float& hi) {
    union { unsigned int x; float f; } c0, c1;
    c0.x = u << 16; c1.x = u & 0xffff0000u;
    lo = c0.f; hi = c1.f;
}
__device__ __forceinline__ float silu(float x) {
    return x * __builtin_amdgcn_rcpf(1.f + __builtin_amdgcn_exp2f(-LOG2E * x));
}

// ---------------------------------------------------------------------------
// Weight prepack: fp32 -> bf16 (RNE). Segments:
//   ip_w 131072 | in_w 524288 | xproj_w 49152 | dt_w 16384
// ---------------------------------------------------------------------------
__global__ __launch_bounds__(256)
void pack_weights(const float* __restrict__ s0, const float* __restrict__ s1,
                  const float* __restrict__ s2, const float* __restrict__ s3,
                  u16* __restrict__ dst)
{
    int idx = (blockIdx.x * 256 + threadIdx.x) * 8;
    const float* src; int off;
    if (idx < 131072)      { src = s0; off = idx; }
    else if (idx < 655360) { src = s1; off = idx - 131072; }
    else if (idx < 704512) { src = s2; off = idx - 655360; }
    else                   { src = s3; off = idx - 704512; }
    float4 f0 = *(const float4*)(src + off);
    float4 f1 = *(const float4*)(src + off + 4);
    union { u16 s[8]; uint4 v; } t;
    t.s[0] = f2b(f0.x); t.s[1] = f2b(f0.y); t.s[2] = f2b(f0.z); t.s[3] = f2b(f0.w);
    t.s[4] = f2b(f1.x); t.s[5] = f2b(f1.y); t.s[6] = f2b(f1.z); t.s[7] = f2b(f1.w);
    *(uint4*)(dst + idx) = t.v;
}

// ---------------------------------------------------------------------------
// Step-1 GEMM (128x128 tile, BK=32): hbuf = x @ ip_w^T + ip_b. A fp32.
// ---------------------------------------------------------------------------
__global__ __launch_bounds__(256)
void gemm_in(const float* __restrict__ A32, const u16* __restrict__ Wb,
             const float* __restrict__ bias, u16* __restrict__ C)
{   // M=8192, N=256, K=512, lda=512, ldw=512, ldc=256
    __shared__ u16 sh[10240];
    u16* As = sh;
    u16* Ws = sh + 5120;
    const int tid  = threadIdx.x;
    const int n0   = blockIdx.x * 128;
    const int m0   = blockIdx.y * 128;
    const int w    = tid >> 6;
    const int lane = tid & 63;
    const int r16  = lane & 15;
    const int q    = lane >> 4;
    const int wm   = (w >> 1) * 64;
    const int wn   = (w & 1) * 64;

    f32x4 acc[4][4];
    #pragma unroll
    for (int i = 0; i < 4; ++i)
        #pragma unroll
        for (int j = 0; j < 4; ++j) acc[i][j] = (f32x4){0.f, 0.f, 0.f, 0.f};

    for (int kt = 0; kt < 16; ++kt) {
        #pragma unroll
        for (int rr = 0; rr < 2; ++rr) {
            int idx = rr * 256 + tid;
            int row = idx >> 2;
            int col = (kt << 5) + (idx & 3) * 8;
            {   // A fp32 -> bf16
                const float* sp = A32 + (size_t)(m0 + row) * 512 + col;
                float4 f0 = *(const float4*)sp;
                float4 f1 = *(const float4*)(sp + 4);
                union { u16 s[8]; uint4 v; } t;
                t.s[0] = f2b(f0.x); t.s[1] = f2b(f0.y);
                t.s[2] = f2b(f0.z); t.s[3] = f2b(f0.w);
                t.s[4] = f2b(f1.x); t.s[5] = f2b(f1.y);
                t.s[6] = f2b(f1.z); t.s[7] = f2b(f1.w);
                *(uint4*)(&As[row * 40 + (idx & 3) * 8]) = t.v;
            }
            if (row < 256 - n0 || true) {   // N=256: rows 0..127 valid for both n-blocks
                uint4 v = *(const uint4*)(Wb + (size_t)(n0 + row) * 512 + col);
                *(uint4*)(&Ws[row * 40 + (idx & 3) * 8]) = v;
            }
        }
        __syncthreads();
        bf16x8 af[4], wf[4];
        #pragma unroll
        for (int i = 0; i < 4; ++i)
            af[i] = *(const bf16x8*)(&As[(wm + i * 16 + r16) * 40 + q * 8]);
        #pragma unroll
        for (int j = 0; j < 4; ++j)
            wf[j] = *(const bf16x8*)(&Ws[(wn + j * 16 + r16) * 40 + q * 8]);
        #pragma unroll
        for (int i = 0; i < 4; ++i)
            #pragma unroll
            for (int j = 0; j < 4; ++j)
                acc[i][j] = __builtin_amdgcn_mfma_f32_16x16x32_bf16(af[i], wf[j], acc[i][j], 0, 0, 0);
        __syncthreads();
    }
    #pragma unroll
    for (int j = 0; j < 4; ++j) {
        int n = n0 + wn + j * 16 + r16;
        float bv = bias[n];
        #pragma unroll
        for (int i = 0; i < 4; ++i)
            #pragma unroll
            for (int rg = 0; rg < 4; ++rg) {
                int m = m0 + wm + i * 16 + q * 4 + rg;
                C[(size_t)m * 256 + n] = f2b(acc[i][j][rg] + bv);
            }
    }
}

// ---------------------------------------------------------------------------
// Step-2 GEMM, double-buffered: xzT[z] = (hbuf(_flip z) @ in_w[z]^T)^T.
// M=8192, N=1024/dir, K=256. BK=64: 32 MFMA per barrier pair; kt+1's 8
// global loads issued after barrier, consumed at next LDS write (latency
// hidden behind MFMA+ds_read). CTRANS epilogue via LDS transpose.
// ---------------------------------------------------------------------------
__global__ __launch_bounds__(256)
void gemm2db(const u16* __restrict__ A, const u16* __restrict__ Wb,
             u16* __restrict__ C)
{
    __shared__ u16 sh[18432];       // As[128*72] | Ws[128*72]; epilogue reuses
    u16* As = sh;
    u16* Ws = sh + 9216;
    const int z = blockIdx.z;
    const u16* Wz = Wb + (size_t)z * 1024 * 256;
    u16* Cz = C + (size_t)z * 1024 * 8192;

    const int tid  = threadIdx.x;
    const int n0   = blockIdx.x * 128;
    const int m0   = blockIdx.y * 128;
    const int w    = tid >> 6;
    const int lane = tid & 63;
    const int r16  = lane & 15;
    const int q    = lane >> 4;
    const int wm   = (w >> 1) * 64;
    const int wn   = (w & 1) * 64;
    const int trow = tid >> 3;      // 0..31
    const int tseg = tid & 7;       // 0..7

    f32x4 acc[4][4];
    #pragma unroll
    for (int i = 0; i < 4; ++i)
        #pragma unroll
        for (int j = 0; j < 4; ++j) acc[i][j] = (f32x4){0.f, 0.f, 0.f, 0.f};

    uint4 ar[4], wr[4];
    #define G2_LOAD(KT_)                                                      \
        _Pragma("unroll")                                                     \
        for (int rr = 0; rr < 4; ++rr) {                                      \
            int row = rr * 32 + trow;                                         \
            int col = ((KT_) << 6) + tseg * 8;                                \
            int m   = m0 + row;                                               \
            int src = z ? ((m & ~2047) | (2047 - (m & 2047))) : m;            \
            ar[rr] = *(const uint4*)(A + (size_t)src * 256 + col);            \
            wr[rr] = *(const uint4*)(Wz + (size_t)(n0 + row) * 256 + col);    \
        }
    G2_LOAD(0);
    for (int kt = 0; kt < 4; ++kt) {
        __syncthreads();
        #pragma unroll
        for (int rr = 0; rr < 4; ++rr) {
            int row = rr * 32 + trow;
            *(uint4*)(&As[row * 72 + tseg * 8]) = ar[rr];
            *(uint4*)(&Ws[row * 72 + tseg * 8]) = wr[rr];
        }
        __syncthreads();
        if (kt < 3) { G2_LOAD(kt + 1); }
        #pragma unroll
        for (int kh = 0; kh < 2; ++kh) {
            bf16x8 af[4], wf[4];
            #pragma unroll
            for (int i = 0; i < 4; ++i)
                af[i] = *(const bf16x8*)(&As[(wm + i * 16 + r16) * 72 + kh * 32 + q * 8]);
            #pragma unroll
            for (int j = 0; j < 4; ++j)
                wf[j] = *(const bf16x8*)(&Ws[(wn + j * 16 + r16) * 72 + kh * 32 + q * 8]);
            #pragma unroll
            for (int i = 0; i < 4; ++i)
                #pragma unroll
                for (int j = 0; j < 4; ++j)
                    acc[i][j] = __builtin_amdgcn_mfma_f32_16x16x32_bf16(af[i], wf[j], acc[i][j], 0, 0, 0);
        }
    }
    #undef G2_LOAD
    // CTRANS epilogue: two n-halves of 64 rows through LDS (stride 132)
    __syncthreads();
    #pragma unroll
    for (int h = 0; h < 2; ++h) {
        if ((w & 1) == h) {
            #pragma unroll
            for (int j = 0; j < 4; ++j)
                #pragma unroll
                for (int i = 0; i < 4; ++i) {
                    union { u16 s[4]; uint2 v; } pk;
                    #pragma unroll
                    for (int rg = 0; rg < 4; ++rg) pk.s[rg] = f2b(acc[i][j][rg]);
                    *(uint2*)(&sh[(j * 16 + r16) * 132 + wm + i * 16 + q * 4]) = pk.v;
                }
        }
        __syncthreads();
        int row = tid >> 2, part = tid & 3;
        const u16* sp2 = &sh[row * 132 + part * 32];
        u16* dp = Cz + (size_t)(n0 + h * 64 + row) * 8192 + m0 + part * 32;
        uint4 v0 = *(const uint4*)(sp2);
        uint4 v1 = *(const uint4*)(sp2 + 8);
        uint4 v2 = *(const uint4*)(sp2 + 16);
        uint4 v3 = *(const uint4*)(sp2 + 24);
        ((uint4*)dp)[0] = v0; ((uint4*)dp)[1] = v1;
        ((uint4*)dp)[2] = v2; ((uint4*)dp)[3] = v3;
        __syncthreads();
    }
}

// ---------------------------------------------------------------------------
// 64x64 MFMA GEMM (skinny N/K, steps 4-5). W bf16 prepacked. A bf16.
// ATRANS: A stored [K][M], rows >= K read as 0. CTRANS via LDS transpose.
// ACT: 0 none, 1 softplus.
// ---------------------------------------------------------------------------
template<int ACT, int ATRANS, int CTRANS>
__global__ __launch_bounds__(256)
void gemm64(const u16* __restrict__ A16, const u16* __restrict__ Wb,
            const float* __restrict__ bias, u16* __restrict__ C,
            int M, int N, int K, int lda, int ldw, int ldc,
            size_t azs, size_t wzs, size_t czs, int bzs)
{
    __shared__ u16 sh[5120];
    u16* As = sh;
    u16* Ws = sh + 2560;
    const int z = blockIdx.z;
    Wb += (size_t)z * wzs;
    C  += (size_t)z * czs;
    if (bias) bias += (size_t)z * bzs;
    const u16* A = A16 + (size_t)z * azs;

    const int tid  = threadIdx.x;
    const int n0   = blockIdx.x * 64;
    const int m0   = blockIdx.y * 64;
    const int r    = tid >> 2;
    const int seg  = tid & 3;
    const int w    = tid >> 6;
    const int lane = tid & 63;
    const int r16  = lane & 15;
    const int q    = lane >> 4;

    f32x4 acc[4];
    #pragma unroll
    for (int i = 0; i < 4; ++i) acc[i] = (f32x4){0.f, 0.f, 0.f, 0.f};

    const int KT = (K + 31) >> 5;
    for (int kt = 0; kt < KT; ++kt) {
        const int kk = (kt << 5) + seg * 8;
        if (ATRANS) {
            int k  = tid >> 3;
            int sg = tid & 7;
            int kd = (kt << 5) + k;
            uint4 v = (uint4){0, 0, 0, 0};
            if (kd < K) v = *(const uint4*)(A + (size_t)kd * lda + m0 + sg * 8);
            const u16* vs = (const u16*)&v;
            #pragma unroll
            for (int e = 0; e < 8; ++e) As[(sg * 8 + e) * 40 + k] = vs[e];
        } else {
            const u16* sp = A + (size_t)(m0 + r) * lda;
            union { u16 s[8]; uint4 v; } t;
            if (kk + 8 <= K) {
                t.v = *(const uint4*)(sp + kk);
            } else {
                #pragma unroll
                for (int e = 0; e < 8; ++e)
                    t.s[e] = ((kk + e) < K) ? sp[kk + e] : (u16)0;
            }
            *(uint4*)(&As[r * 40 + seg * 8]) = t.v;
        }
        {
            int n = n0 + r;
            const u16* sp = Wb + (size_t)n * ldw;
            union { u16 s[8]; uint4 v; } t;
            if (n < N && kk + 8 <= K) {
                t.v = *(const uint4*)(sp + kk);
            } else {
                #pragma unroll
                for (int e = 0; e < 8; ++e)
                    t.s[e] = (n < N && (kk + e) < K) ? sp[kk + e] : (u16)0;
            }
            *(uint4*)(&Ws[r * 40 + seg * 8]) = t.v;
        }
        __syncthreads();
        bf16x8 af = *(const bf16x8*)(&As[(w * 16 + r16) * 40 + q * 8]);
        #pragma unroll
        for (int nt = 0; nt < 4; ++nt) {
            bf16x8 wf = *(const bf16x8*)(&Ws[(nt * 16 + r16) * 40 + q * 8]);
            acc[nt] = __builtin_amdgcn_mfma_f32_16x16x32_bf16(af, wf, acc[nt], 0, 0, 0);
        }
        __syncthreads();
    }
    if (CTRANS) {
        #pragma unroll
        for (int nt = 0; nt < 4; ++nt) {
            float bv = bias ? bias[n0 + nt * 16 + r16] : 0.f;
            union { u16 s[4]; uint2 v; } pk;
            #pragma unroll
            for (int rg = 0; rg < 4; ++rg) {
                float v = acc[nt][rg] + bv;
                if (ACT == 1) v = (v > 20.f) ? v : __logf(1.f + __expf(v));
                pk.s[rg] = f2b(v);
            }
            *(uint2*)(&sh[(nt * 16 + r16) * 68 + w * 16 + q * 4]) = pk.v;
        }
        __syncthreads();
        int row = tid >> 2, part = tid & 3;
        if (n0 + row < N) {
            const u16* sp2 = &sh[row * 68 + part * 16];
            u16* dp = C + (size_t)(n0 + row) * ldc + m0 + part * 16;
            uint4 v0 = *(const uint4*)(sp2);
            uint4 v1 = *(const uint4*)(sp2 + 8);
            ((uint4*)dp)[0] = v0; ((uint4*)dp)[1] = v1;
        }
    } else {
        #pragma unroll
        for (int nt = 0; nt < 4; ++nt) {
            int n = n0 + nt * 16 + r16;
            if (n >= N) continue;
            float bv = bias ? bias[n] : 0.f;
            #pragma unroll
            for (int rg = 0; rg < 4; ++rg) {
                int m = m0 + w * 16 + q * 4 + rg;
                float v = acc[nt][rg] + bv;
                if (ACT == 1) v = (v > 20.f) ? v : __logf(1.f + __expf(v));
                C[(size_t)m * ldc + n] = f2b(v);
            }
        }
    }
}

// ---------------------------------------------------------------------------
// Depthwise causal conv (4 taps) + silu, time-major.
// ---------------------------------------------------------------------------
__global__ __launch_bounds__(256)
void conv_silu_T(const u16* __restrict__ xzT, const float* __restrict__ cw,
                 const float* __restrict__ cb, u16* __restrict__ uT)
{
    int g    = blockIdx.x * 256 + threadIdx.x;
    int tile = g & 63;
    int b    = (g >> 6) & 3;
    int ch   = (g >> 8) & 511;
    int d    = g >> 17;
    int l0   = tile * 32;
    const u16* row = xzT + ((size_t)d * 1024 + ch) * 8192 + b * 2048;

    union { u16 s[40]; uint4 v[5]; } wd;
    wd.v[0] = (tile > 0) ? *(const uint4*)(row + l0 - 8) : (uint4){0, 0, 0, 0};
    #pragma unroll
    for (int i = 0; i < 4; ++i) wd.v[1 + i] = *(const uint4*)(row + l0 + i * 8);

    const float* wp = cw + (size_t)(d * 512 + ch) * 4;
    float c0 = wp[0], c1 = wp[1], c2 = wp[2], c3 = wp[3];
    float bias = cb[d * 512 + ch];

    union { u16 s[32]; uint4 v[4]; } o;
    #pragma unroll
    for (int i = 0; i < 32; ++i) {
        float acc = bias + c0 * b2f(wd.s[5 + i]) + c1 * b2f(wd.s[6 + i])
                         + c2 * b2f(wd.s[7 + i]) + c3 * b2f(wd.s[8 + i]);
        o.s[i] = f2b(silu(acc));
    }
    u16* orow = uT + ((size_t)d * 512 + ch) * 8192 + b * 2048 + l0;
    #pragma unroll
    for (int i = 0; i < 4; ++i) ((uint4*)orow)[i] = o.v[i];
}

// ---------------------------------------------------------------------------
// Single-pass chunked associative scan, 8 states/thread, dt/u/z prefetch.
// ---------------------------------------------------------------------------
__global__ __launch_bounds__(256)
void scan_kernel(const u16* __restrict__ xzT, const u16* __restrict__ uT,
                 const u16* __restrict__ dbcT, const float* __restrict__ A_log,
                 const float* __restrict__ Dp, float* __restrict__ gsum)
{
    __shared__ float part[4];
    const int tid  = threadIdx.x;
    const int wv   = tid >> 6;
    const int lane = tid & 63;
    const int blk  = blockIdx.x;              // 0..2047
    const int bd   = blk >> 8;
    const int d    = bd >> 2, b = bd & 3;
    const int ch   = (blk & 255) * 2 + (wv >> 1);
    const int nh   = (wv & 1) * 8;

    const u16* pdt = xzT + ((size_t)d * 1024 + ch) * 8192 + b * 2048 + lane * 32;
    const u16* pz  = xzT + ((size_t)d * 1024 + 512 + ch) * 8192 + b * 2048 + lane * 32;
    const u16* pu  = uT + ((size_t)d * 512 + ch) * 8192 + b * 2048 + lane * 32;
    const u16* pB  = dbcT + ((size_t)d * 48 + 16 + nh) * 8192 + b * 2048 + lane * 32;
    const u16* pC  = dbcT + ((size_t)d * 48 + 32 + nh) * 8192 + b * 2048 + lane * 32;

    float a[8];
    #pragma unroll
    for (int n = 0; n < 8; ++n)
        a[n] = -LOG2E * __expf(A_log[(d * 512 + ch) * 16 + nh + n]);
    const float DvEff = (wv & 1) ? 0.f : Dp[d * 512 + ch];

    float P[8], S[8], beta[8];
    #pragma unroll
    for (int n = 0; n < 8; ++n) { P[n] = 1.f; S[n] = 0.f; beta[n] = 0.f; }
    float alpha = 0.f;

    uint4 vdt = *(const uint4*)(pdt);
    uint4 vu  = *(const uint4*)(pu);
    uint4 vz  = *(const uint4*)(pz);

    #pragma unroll 1
    for (int gq = 0; gq < 4; ++gq) {
        int nxt = (gq < 3) ? (gq + 1) * 8 : 0;
        uint4 ndt = *(const uint4*)(pdt + nxt);
        uint4 nu  = *(const uint4*)(pu + nxt);
        uint4 nz  = *(const uint4*)(pz + nxt);
        const u16* ds = (const u16*)&vdt;
        const u16* us = (const u16*)&vu;
        const u16* zs = (const u16*)&vz;
        float dtv[8], duv[8], gv[8];
        #pragma unroll
        for (int s = 0; s < 8; ++s) {
            float dt = b2f(ds[s]), uv = b2f(us[s]), zv = b2f(zs[s]);
            dtv[s] = dt;
            duv[s] = dt * uv;
            float g = silu(zv);
            gv[s] = g;
            alpha = fmaf(g * uv, DvEff, alpha);
        }
        #pragma unroll
        for (int n = 0; n < 8; ++n) {
            uint4 Bq = *(const uint4*)(pB + (size_t)n * 8192 + gq * 8);
            uint4 Cq = *(const uint4*)(pC + (size_t)n * 8192 + gq * 8);
            unsigned int bw[4] = {Bq.x, Bq.y, Bq.z, Bq.w};
            unsigned int cw2[4] = {Cq.x, Cq.y, Cq.z, Cq.w};
            float tp = P[n], ts = S[n], tb = beta[n], an = a[n];
            #pragma unroll
            for (int w2 = 0; w2 < 4; ++w2) {
                float B0, B1, C0, C1;
                unpk2(bw[w2], B0, B1);
                unpk2(cw2[w2], C0, C1);
                int s0 = 2 * w2, s1 = s0 + 1;
                float dA0 = __builtin_amdgcn_exp2f(dtv[s0] * an);
                ts = fmaf(dA0, ts, duv[s0] * B0);
                tp *= dA0;
                float gC0 = gv[s0] * C0;
                alpha = fmaf(gC0, ts, alpha);
                tb = fmaf(gC0, tp, tb);
                float dA1 = __builtin_amdgcn_exp2f(dtv[s1] * an);
                ts = fmaf(dA1, ts, duv[s1] * B1);
                tp *= dA1;
                float gC1 = gv[s1] * C1;
                alpha = fmaf(gC1, ts, alpha);
                tb = fmaf(gC1, tp, tb);
            }
            P[n] = tp; S[n] = ts; beta[n] = tb;
        }
        vdt = ndt; vu = nu; vz = nz;
    }
    #pragma unroll
    for (int off = 1; off < 64; off <<= 1) {
        #pragma unroll
        for (int n = 0; n < 8; ++n) {
            float Pp = __shfl_up(P[n], off);
            float Sp = __shfl_up(S[n], off);
            Pp = (lane >= off) ? Pp : 1.f;
            Sp = (lane >= off) ? Sp : 0.f;
            S[n] = fmaf(P[n], Sp, S[n]);
            P[n] *= Pp;
        }
    }
    float gacc = alpha;
    #pragma unroll
    for (int n = 0; n < 8; ++n) {
        float Hs = __shfl_up(S[n], 1);
        float h0 = (lane == 0) ? 0.f : Hs;
        gacc = fmaf(beta[n], h0, gacc);
    }
    #pragma unroll
    for (int off = 1; off < 64; off <<= 1) gacc += __shfl_xor(gacc, off);
    if (lane == 0) part[wv] = gacc;
    __syncthreads();
    if (tid < 2)
        gsum[bd * 512 + (blk & 255) * 2 + tid] = part[tid * 2] + part[tid * 2 + 1];
}

// ---------------------------------------------------------------------------
// Final projections (two wave-cooperative GEMVs).
// ---------------------------------------------------------------------------
__global__ __launch_bounds__(256)
void final_embd(const float* __restrict__ gsum, const float* __restrict__ out_w,
                float* __restrict__ embd)
{
    const int b  = blockIdx.x >> 3;
    const int jg = blockIdx.x & 7;
    const int wv = threadIdx.x >> 6;
    const int lane = threadIdx.x & 63;
    for (int t = 0; t < 16; ++t) {
        int j  = jg * 64 + wv * 16 + t;
        int dd = j >> 8, jj = j & 255;
        const float* wp = out_w + (size_t)(dd * 256 + jj) * 512 + lane * 8;
        const float* gp = gsum + (size_t)(dd * 4 + b) * 512 + lane * 8;
        float4 w0 = *(const float4*)wp;
        float4 w1 = *(const float4*)(wp + 4);
        float4 g0 = *(const float4*)gp;
        float4 g1 = *(const float4*)(gp + 4);
        float s = w0.x * g0.x + w0.y * g0.y + w0.z * g0.z + w0.w * g0.w
                + w1.x * g1.x + w1.y * g1.y + w1.z * g1.z + w1.w * g1.w;
        #pragma unroll
        for (int off = 1; off < 64; off <<= 1) s += __shfl_xor(s, off);
        if (lane == 0) embd[b * 512 + j] = s * (1.0f / 2048.0f);
    }
}

__global__ __launch_bounds__(256)
void final_out(const float* __restrict__ embd, const float* __restrict__ op_w,
               const float* __restrict__ op_b, float* __restrict__ out)
{
    const int b  = blockIdx.x >> 2;
    const int ig = blockIdx.x & 3;
    const int wv = threadIdx.x >> 6;
    const int lane = threadIdx.x & 63;
    for (int t = 0; t < 16; ++t) {
        int i = ig * 64 + wv * 16 + t;
        const float* wp = op_w + (size_t)i * 512 + lane * 8;
        const float* ep = embd + (size_t)b * 512 + lane * 8;
        float4 w0 = *(const float4*)wp;
        float4 w1 = *(const float4*)(wp + 4);
        float4 e0 = *(const float4*)ep;
        float4 e1 = *(const float4*)(ep + 4);
        float s = w0.x * e0.x + w0.y * e0.y + w0.z * e0.z + w0.w * e0.w
                + w1.x * e1.x + w1.y * e1.y + w1.z * e1.z + w1.w * e1.w;
        #pragma unroll
        for (int off = 1; off < 64; off <<= 1) s += __shfl_xor(s, off);
        if (lane == 0) out[b * 256 + i] = s + op_b[i];
    }
}

// ---------------------------------------------------------------------------
extern "C" void kernel_launch(void* const* d_in, const int* in_sizes, int n_in,
                              void* d_out, int out_size, void* d_ws, size_t ws_size,
                              hipStream_t stream)
{
    (void)in_sizes; (void)n_in; (void)out_size; (void)ws_size;
    const float* x       = (const float*)d_in[0];
    const float* ip_w    = (const float*)d_in[1];
    const float* ip_b    = (const float*)d_in[2];
    const float* in_w    = (const float*)d_in[3];
    const float* conv_w  = (const float*)d_in[4];
    const float* conv_b  = (const float*)d_in[5];
    const float* xproj_w = (const float*)d_in[6];
    const float* dt_w    = (const float*)d_in[7];
    const float* dt_b    = (const float*)d_in[8];
    const float* A_log   = (const float*)d_in[9];
    const float* Dp      = (const float*)d_in[10];
    const float* out_w   = (const float*)d_in[11];
    const float* op_w    = (const float*)d_in[12];
    const float* op_b    = (const float*)d_in[13];
    float* out = (float*)d_out;

    // Workspace (53,370,880 B): xzT | uT (hbuf alias) | dbcT | gsum | wpack | embd
    char* ws = (char*)d_ws;
    u16*   xzT  = (u16*)(ws + 0);
    u16*   uT   = (u16*)(ws + 33554432);
    u16*   hbuf = (u16*)(ws + 33554432);
    u16*   dbcT = (u16*)(ws + 50331648);
    float* gsum = (float*)(ws + 51904512);
    u16*   wpk  = (u16*)(ws + 51920896);
    float* embd = (float*)(ws + 53362688);
    u16*   ipw_b    = wpk;               // 131072
    u16*   inw_b    = wpk + 131072;      // 524288
    u16*   xprojw_b = wpk + 655360;      // 49152
    u16*   dtw_b    = wpk + 704512;      // 16384

    dim3 blk(256);

    // 0) prepack weights fp32->bf16
    pack_weights<<<dim3(352), blk, 0, stream>>>(ip_w, in_w, xproj_w, dt_w, wpk);

    // 1) in_proj: hbuf = x @ ip_w^T + ip_b   [8192,256]
    gemm_in<<<dim3(2, 64), blk, 0, stream>>>(x, ipw_b, ip_b, hbuf);

    // 2) xzT[d] = (hbuf(_flip d) @ in_w[d]^T)^T  (BK=64, double-buffered)
    gemm2db<<<dim3(8, 64, 2), blk, 0, stream>>>(hbuf, inw_b, xzT);

    // 3) uT = silu(causal_conv(xiT) + cb)
    conv_silu_T<<<dim3(1024), blk, 0, stream>>>(xzT, conv_w, conv_b, uT);

    // 4) dbcT[d] = ((uT[d])^T @ xproj_w[d]^T)^T   [48][8192] n-major
    gemm64<0, 1, 1><<<dim3(1, 128, 2), blk, 0, stream>>>(
        uT, xprojw_b, nullptr, dbcT, 8192, 48, 512, 8192, 512, 8192,
        (size_t)512 * 8192, (size_t)48 * 512, (size_t)48 * 8192, 0);

    // 5) dtT[d] = softplus(dbcT[0:16]^T @ dt_w[d]^T + dt_b[d])^T -> xzT rows 0:512
    gemm64<1, 1, 1><<<dim3(8, 128, 2), blk, 0, stream>>>(
        dbcT, dtw_b, dt_b, xzT, 8192, 512, 16, 8192, 16, 8192,
        (size_t)48 * 8192, (size_t)512 * 16, (size_t)1024 * 8192, 512);

    // 6) single-pass chunked scan + gated mean-pool
    scan_kernel<<<dim3(2048), blk, 0, stream>>>(xzT, uT, dbcT, A_log, Dp, gsum);

    // 7) final projections
    final_embd<<<dim3(32), blk, 0, stream>>>(gsum, out_w, embd);
    final_out<<<dim3(16), blk, 0, stream>>>(embd, op_w, op_b, out);
}

// Round 12
// 280.794 us; speedup vs baseline: 1.0411x; 1.0411x over previous
//
#include <hip/hip_runtime.h>
#include <stdint.h>

// MambaEncoder on MI355X (gfx950).
// ALL inputs and the output are FLOAT32. Intermediates bf16 in workspace,
// TIME-MAJOR; dbc n-major. R12: steps 1+2 fused by associativity —
// W2[d] = in_w[d] @ ip_w, bias2 = in_w @ ip_b, then xzT = (x(_flip) @ W2^T
// + bias2)^T in ONE K=512 GEMM (R11's BK=64 dbuf REVERTED: +28 us from
// LDS/VGPR occupancy loss). CTRANS epilogues via LDS transpose.
// Scan: single-pass chunked associative scan, 8 states/thread (R10 version).

typedef unsigned short u16;
typedef __bf16 bf16x8 __attribute__((ext_vector_type(8)));
typedef float f32x4 __attribute__((ext_vector_type(4)));

#define LOG2E 1.44269504088896f

__device__ __forceinline__ float b2f(u16 h) {
    union { unsigned int u; float f; } c; c.u = ((unsigned int)h) << 16; return c.f;
}
__device__ __forceinline__ u16 f2b(float f) {   // round-to-nearest-even
    union { float f; unsigned int u; } c; c.f = f;
    unsigned int r = c.u + 0x7FFFu + ((c.u >> 16) & 1u);
    return (u16)(r >> 16);
}
__device__ __forceinline__ void unpk2(unsigned int u, float& lo, float& hi) {
    union { unsigned int x; float f; } c0, c1;
    c0.x = u << 16; c1.x = u & 0xffff0000u;
    lo = c0.f; hi = c1.f;
}
__device__ __forceinline__ float silu(float x) {
    return x * __builtin_amdgcn_rcpf(1.f + __builtin_amdgcn_exp2f(-LOG2E * x));
}

// ---------------------------------------------------------------------------
// Weight prepack: fp32 -> bf16 (RNE). Segment 0 is ip_w TRANSPOSED
// (ipwT[j][c] = ip_w[c][j], for the W2 GEMM's W operand). Segments:
//   ipwT 131072 | in_w 524288 | xproj_w 49152 | dt_w 16384
// ---------------------------------------------------------------------------
__global__ __launch_bounds__(256)
void pack_weights(const float* __restrict__ s0, const float* __restrict__ s1,
                  const float* __restrict__ s2, const float* __restrict__ s3,
                  u16* __restrict__ dst)
{
    int idx = (blockIdx.x * 256 + threadIdx.x) * 8;   // grid 352
    union { u16 s[8]; uint4 v; } t;
    if (idx < 131072) {
        int j = idx >> 8, c = idx & 255;              // 8 consecutive c
        #pragma unroll
        for (int e = 0; e < 8; ++e) t.s[e] = f2b(s0[(size_t)(c + e) * 512 + j]);
    } else {
        const float* src; int off;
        if (idx < 655360)      { src = s1; off = idx - 131072; }
        else if (idx < 704512) { src = s2; off = idx - 655360; }
        else                   { src = s3; off = idx - 704512; }
        float4 f0 = *(const float4*)(src + off);
        float4 f1 = *(const float4*)(src + off + 4);
        t.s[0] = f2b(f0.x); t.s[1] = f2b(f0.y); t.s[2] = f2b(f0.z); t.s[3] = f2b(f0.w);
        t.s[4] = f2b(f1.x); t.s[5] = f2b(f1.y); t.s[6] = f2b(f1.z); t.s[7] = f2b(f1.w);
    }
    *(uint4*)(dst + idx) = t.v;
}

// ---------------------------------------------------------------------------
// Pack x fp32 -> bf16 (halves gemm_xz A traffic). 4,194,304 elems, grid 2048.
// ---------------------------------------------------------------------------
__global__ __launch_bounds__(256)
void pack_x(const float* __restrict__ x, u16* __restrict__ xb)
{
    int idx = (blockIdx.x * 256 + threadIdx.x) * 8;
    float4 f0 = *(const float4*)(x + idx);
    float4 f1 = *(const float4*)(x + idx + 4);
    union { u16 s[8]; uint4 v; } t;
    t.s[0] = f2b(f0.x); t.s[1] = f2b(f0.y); t.s[2] = f2b(f0.z); t.s[3] = f2b(f0.w);
    t.s[4] = f2b(f1.x); t.s[5] = f2b(f1.y); t.s[6] = f2b(f1.z); t.s[7] = f2b(f1.w);
    *(uint4*)(xb + idx) = t.v;
}

// ---------------------------------------------------------------------------
// bias2[n] = dot(in_w[n, 0:256], ip_b), n in [0,2048). Wave per row-group.
// ---------------------------------------------------------------------------
__global__ __launch_bounds__(256)
void gemv_bias2(const float* __restrict__ in_w, const float* __restrict__ ip_b,
                float* __restrict__ bias2)
{
    const int wv = threadIdx.x >> 6, lane = threadIdx.x & 63;
    for (int t = 0; t < 16; ++t) {
        int n = blockIdx.x * 64 + wv * 16 + t;    // grid 32
        float4 w0 = *(const float4*)(in_w + (size_t)n * 256 + lane * 4);
        float4 b0 = *(const float4*)(ip_b + lane * 4);
        float s = w0.x * b0.x + w0.y * b0.y + w0.z * b0.z + w0.w * b0.w;
        #pragma unroll
        for (int off = 1; off < 64; off <<= 1) s += __shfl_xor(s, off);
        if (lane == 0) bias2[n] = s;
    }
}

// ---------------------------------------------------------------------------
// Fused step-1+2 GEMM (128x128 tile, BK=32, R10-proven structure):
// xzT[z][n][m] = sum_k xb(flip_z)[m][k]*W2[z*1024+n][k] + bias2[z*1024+n].
// M=8192, N=1024/dir, K=512 (16 iters). CTRANS epilogue via LDS transpose.
// ---------------------------------------------------------------------------
__global__ __launch_bounds__(256)
void gemm_xz(const u16* __restrict__ A, const u16* __restrict__ W2,
             const float* __restrict__ bias2, u16* __restrict__ C)
{
    __shared__ u16 sh[10240];       // As 128x40 | Ws 128x40 ; epilogue reuses
    u16* As = sh;
    u16* Ws = sh + 5120;
    const int z = blockIdx.z;
    const u16* Wz = W2 + (size_t)z * 1024 * 512;
    const float* bz = bias2 + z * 1024;
    u16* Cz = C + (size_t)z * 1024 * 8192;

    const int tid  = threadIdx.x;
    const int n0   = blockIdx.x * 128;
    const int m0   = blockIdx.y * 128;
    const int w    = tid >> 6;
    const int lane = tid & 63;
    const int r16  = lane & 15;
    const int q    = lane >> 4;
    const int wm   = (w >> 1) * 64;
    const int wn   = (w & 1) * 64;

    f32x4 acc[4][4];
    #pragma unroll
    for (int i = 0; i < 4; ++i)
        #pragma unroll
        for (int j = 0; j < 4; ++j) acc[i][j] = (f32x4){0.f, 0.f, 0.f, 0.f};

    for (int kt = 0; kt < 16; ++kt) {
        #pragma unroll
        for (int rr = 0; rr < 2; ++rr) {
            int idx = rr * 256 + tid;
            int row = idx >> 2;
            int col = (kt << 5) + (idx & 3) * 8;
            int m   = m0 + row;
            int src = z ? ((m & ~2047) | (2047 - (m & 2047))) : m;
            *(uint4*)(&As[row * 40 + (idx & 3) * 8]) =
                *(const uint4*)(A + (size_t)src * 512 + col);
            *(uint4*)(&Ws[row * 40 + (idx & 3) * 8]) =
                *(const uint4*)(Wz + (size_t)(n0 + row) * 512 + col);
        }
        __syncthreads();
        bf16x8 af[4], wf[4];
        #pragma unroll
        for (int i = 0; i < 4; ++i)
            af[i] = *(const bf16x8*)(&As[(wm + i * 16 + r16) * 40 + q * 8]);
        #pragma unroll
        for (int j = 0; j < 4; ++j)
            wf[j] = *(const bf16x8*)(&Ws[(wn + j * 16 + r16) * 40 + q * 8]);
        #pragma unroll
        for (int i = 0; i < 4; ++i)
            #pragma unroll
            for (int j = 0; j < 4; ++j)
                acc[i][j] = __builtin_amdgcn_mfma_f32_16x16x32_bf16(af[i], wf[j], acc[i][j], 0, 0, 0);
        __syncthreads();
    }
    // CTRANS epilogue: two n-halves of 64 rows through LDS (stride 132)
    #pragma unroll
    for (int h = 0; h < 2; ++h) {
        if ((w & 1) == h) {
            #pragma unroll
            for (int j = 0; j < 4; ++j) {
                float bv = bz[n0 + wn + j * 16 + r16];
                #pragma unroll
                for (int i = 0; i < 4; ++i) {
                    union { u16 s[4]; uint2 v; } pk;
                    #pragma unroll
                    for (int rg = 0; rg < 4; ++rg) pk.s[rg] = f2b(acc[i][j][rg] + bv);
                    *(uint2*)(&sh[(j * 16 + r16) * 132 + wm + i * 16 + q * 4]) = pk.v;
                }
            }
        }
        __syncthreads();
        int row = tid >> 2, part = tid & 3;
        const u16* sp2 = &sh[row * 132 + part * 32];
        u16* dp = Cz + (size_t)(n0 + h * 64 + row) * 8192 + m0 + part * 32;
        uint4 v0 = *(const uint4*)(sp2);
        uint4 v1 = *(const uint4*)(sp2 + 8);
        uint4 v2 = *(const uint4*)(sp2 + 16);
        uint4 v3 = *(const uint4*)(sp2 + 24);
        ((uint4*)dp)[0] = v0; ((uint4*)dp)[1] = v1;
        ((uint4*)dp)[2] = v2; ((uint4*)dp)[3] = v3;
        __syncthreads();
    }
}

// ---------------------------------------------------------------------------
// 64x64 MFMA GEMM (W2 precompute + steps 4-5). W bf16 prepacked. A bf16.
// ATRANS: A stored [K][M], rows >= K read as 0. CTRANS via LDS transpose.
// ACT: 0 none, 1 softplus.
// ---------------------------------------------------------------------------
template<int ACT, int ATRANS, int CTRANS>
__global__ __launch_bounds__(256)
void gemm64(const u16* __restrict__ A16, const u16* __restrict__ Wb,
            const float* __restrict__ bias, u16* __restrict__ C,
            int M, int N, int K, int lda, int ldw, int ldc,
            size_t azs, size_t wzs, size_t czs, int bzs)
{
    __shared__ u16 sh[5120];
    u16* As = sh;
    u16* Ws = sh + 2560;
    const int z = blockIdx.z;
    Wb += (size_t)z * wzs;
    C  += (size_t)z * czs;
    if (bias) bias += (size_t)z * bzs;
    const u16* A = A16 + (size_t)z * azs;

    const int tid  = threadIdx.x;
    const int n0   = blockIdx.x * 64;
    const int m0   = blockIdx.y * 64;
    const int r    = tid >> 2;
    const int seg  = tid & 3;
    const int w    = tid >> 6;
    const int lane = tid & 63;
    const int r16  = lane & 15;
    const int q    = lane >> 4;

    f32x4 acc[4];
    #pragma unroll
    for (int i = 0; i < 4; ++i) acc[i] = (f32x4){0.f, 0.f, 0.f, 0.f};

    const int KT = (K + 31) >> 5;
    for (int kt = 0; kt < KT; ++kt) {
        const int kk = (kt << 5) + seg * 8;
        if (ATRANS) {
            int k  = tid >> 3;
            int sg = tid & 7;
            int kd = (kt << 5) + k;
            uint4 v = (uint4){0, 0, 0, 0};
            if (kd < K) v = *(const uint4*)(A + (size_t)kd * lda + m0 + sg * 8);
            const u16* vs = (const u16*)&v;
            #pragma unroll
            for (int e = 0; e < 8; ++e) As[(sg * 8 + e) * 40 + k] = vs[e];
        } else {
            const u16* sp = A + (size_t)(m0 + r) * lda;
            union { u16 s[8]; uint4 v; } t;
            if (kk + 8 <= K) {
                t.v = *(const uint4*)(sp + kk);
            } else {
                #pragma unroll
                for (int e = 0; e < 8; ++e)
                    t.s[e] = ((kk + e) < K) ? sp[kk + e] : (u16)0;
            }
            *(uint4*)(&As[r * 40 + seg * 8]) = t.v;
        }
        {
            int n = n0 + r;
            const u16* sp = Wb + (size_t)n * ldw;
            union { u16 s[8]; uint4 v; } t;
            if (n < N && kk + 8 <= K) {
                t.v = *(const uint4*)(sp + kk);
            } else {
                #pragma unroll
                for (int e = 0; e < 8; ++e)
                    t.s[e] = (n < N && (kk + e) < K) ? sp[kk + e] : (u16)0;
            }
            *(uint4*)(&Ws[r * 40 + seg * 8]) = t.v;
        }
        __syncthreads();
        bf16x8 af = *(const bf16x8*)(&As[(w * 16 + r16) * 40 + q * 8]);
        #pragma unroll
        for (int nt = 0; nt < 4; ++nt) {
            bf16x8 wf = *(const bf16x8*)(&Ws[(nt * 16 + r16) * 40 + q * 8]);
            acc[nt] = __builtin_amdgcn_mfma_f32_16x16x32_bf16(af, wf, acc[nt], 0, 0, 0);
        }
        __syncthreads();
    }
    if (CTRANS) {
        #pragma unroll
        for (int nt = 0; nt < 4; ++nt) {
            float bv = bias ? bias[n0 + nt * 16 + r16] : 0.f;
            union { u16 s[4]; uint2 v; } pk;
            #pragma unroll
            for (int rg = 0; rg < 4; ++rg) {
                float v = acc[nt][rg] + bv;
                if (ACT == 1) v = (v > 20.f) ? v : __logf(1.f + __expf(v));
                pk.s[rg] = f2b(v);
            }
            *(uint2*)(&sh[(nt * 16 + r16) * 68 + w * 16 + q * 4]) = pk.v;
        }
        __syncthreads();
        int row = tid >> 2, part = tid & 3;
        if (n0 + row < N) {
            const u16* sp2 = &sh[row * 68 + part * 16];
            u16* dp = C + (size_t)(n0 + row) * ldc + m0 + part * 16;
            uint4 v0 = *(const uint4*)(sp2);
            uint4 v1 = *(const uint4*)(sp2 + 8);
            ((uint4*)dp)[0] = v0; ((uint4*)dp)[1] = v1;
        }
    } else {
        #pragma unroll
        for (int nt = 0; nt < 4; ++nt) {
            int n = n0 + nt * 16 + r16;
            if (n >= N) continue;
            float bv = bias ? bias[n] : 0.f;
            #pragma unroll
            for (int rg = 0; rg < 4; ++rg) {
                int m = m0 + w * 16 + q * 4 + rg;
                float v = acc[nt][rg] + bv;
                if (ACT == 1) v = (v > 20.f) ? v : __logf(1.f + __expf(v));
                C[(size_t)m * ldc + n] = f2b(v);
            }
        }
    }
}

// ---------------------------------------------------------------------------
// Depthwise causal conv (4 taps) + silu, time-major.
// ---------------------------------------------------------------------------
__global__ __launch_bounds__(256)
void conv_silu_T(const u16* __restrict__ xzT, const float* __restrict__ cw,
                 const float* __restrict__ cb, u16* __restrict__ uT)
{
    int g    = blockIdx.x * 256 + threadIdx.x;
    int tile = g & 63;
    int b    = (g >> 6) & 3;
    int ch   = (g >> 8) & 511;
    int d    = g >> 17;
    int l0   = tile * 32;
    const u16* row = xzT + ((size_t)d * 1024 + ch) * 8192 + b * 2048;

    union { u16 s[40]; uint4 v[5]; } wd;
    wd.v[0] = (tile > 0) ? *(const uint4*)(row + l0 - 8) : (uint4){0, 0, 0, 0};
    #pragma unroll
    for (int i = 0; i < 4; ++i) wd.v[1 + i] = *(const uint4*)(row + l0 + i * 8);

    const float* wp = cw + (size_t)(d * 512 + ch) * 4;
    float c0 = wp[0], c1 = wp[1], c2 = wp[2], c3 = wp[3];
    float bias = cb[d * 512 + ch];

    union { u16 s[32]; uint4 v[4]; } o;
    #pragma unroll
    for (int i = 0; i < 32; ++i) {
        float acc = bias + c0 * b2f(wd.s[5 + i]) + c1 * b2f(wd.s[6 + i])
                         + c2 * b2f(wd.s[7 + i]) + c3 * b2f(wd.s[8 + i]);
        o.s[i] = f2b(silu(acc));
    }
    u16* orow = uT + ((size_t)d * 512 + ch) * 8192 + b * 2048 + l0;
    #pragma unroll
    for (int i = 0; i < 4; ++i) ((uint4*)orow)[i] = o.v[i];
}

// ---------------------------------------------------------------------------
// Single-pass chunked associative scan, 8 states/thread (R10 version —
// R11's prefetch was neutral on dur and cost occupancy).
// ---------------------------------------------------------------------------
__global__ __launch_bounds__(256)
void scan_kernel(const u16* __restrict__ xzT, const u16* __restrict__ uT,
                 const u16* __restrict__ dbcT, const float* __restrict__ A_log,
                 const float* __restrict__ Dp, float* __restrict__ gsum)
{
    __shared__ float part[4];
    const int tid  = threadIdx.x;
    const int wv   = tid >> 6;
    const int lane = tid & 63;
    const int blk  = blockIdx.x;              // 0..2047
    const int bd   = blk >> 8;
    const int d    = bd >> 2, b = bd & 3;
    const int ch   = (blk & 255) * 2 + (wv >> 1);
    const int nh   = (wv & 1) * 8;

    const u16* pdt = xzT + ((size_t)d * 1024 + ch) * 8192 + b * 2048 + lane * 32;
    const u16* pz  = xzT + ((size_t)d * 1024 + 512 + ch) * 8192 + b * 2048 + lane * 32;
    const u16* pu  = uT + ((size_t)d * 512 + ch) * 8192 + b * 2048 + lane * 32;
    const u16* pB  = dbcT + ((size_t)d * 48 + 16 + nh) * 8192 + b * 2048 + lane * 32;
    const u16* pC  = dbcT + ((size_t)d * 48 + 32 + nh) * 8192 + b * 2048 + lane * 32;

    float a[8];
    #pragma unroll
    for (int n = 0; n < 8; ++n)
        a[n] = -LOG2E * __expf(A_log[(d * 512 + ch) * 16 + nh + n]);
    const float DvEff = (wv & 1) ? 0.f : Dp[d * 512 + ch];

    float P[8], S[8], beta[8];
    #pragma unroll
    for (int n = 0; n < 8; ++n) { P[n] = 1.f; S[n] = 0.f; beta[n] = 0.f; }
    float alpha = 0.f;

    #pragma unroll 1
    for (int gq = 0; gq < 4; ++gq) {
        uint4 vdt = *(const uint4*)(pdt + gq * 8);
        uint4 vu  = *(const uint4*)(pu + gq * 8);
        uint4 vz  = *(const uint4*)(pz + gq * 8);
        const u16* ds = (const u16*)&vdt;
        const u16* us = (const u16*)&vu;
        const u16* zs = (const u16*)&vz;
        float dtv[8], duv[8], gv[8];
        #pragma unroll
        for (int s = 0; s < 8; ++s) {
            float dt = b2f(ds[s]), uv = b2f(us[s]), zv = b2f(zs[s]);
            dtv[s] = dt;
            duv[s] = dt * uv;
            float g = silu(zv);
            gv[s] = g;
            alpha = fmaf(g * uv, DvEff, alpha);
        }
        #pragma unroll
        for (int n = 0; n < 8; ++n) {
            uint4 Bq = *(const uint4*)(pB + (size_t)n * 8192 + gq * 8);
            uint4 Cq = *(const uint4*)(pC + (size_t)n * 8192 + gq * 8);
            unsigned int bw[4] = {Bq.x, Bq.y, Bq.z, Bq.w};
            unsigned int cw2[4] = {Cq.x, Cq.y, Cq.z, Cq.w};
            float tp = P[n], ts = S[n], tb = beta[n], an = a[n];
            #pragma unroll
            for (int w2 = 0; w2 < 4; ++w2) {
                float B0, B1, C0, C1;
                unpk2(bw[w2], B0, B1);
                unpk2(cw2[w2], C0, C1);
                int s0 = 2 * w2, s1 = s0 + 1;
                float dA0 = __builtin_amdgcn_exp2f(dtv[s0] * an);
                ts = fmaf(dA0, ts, duv[s0] * B0);
                tp *= dA0;
                float gC0 = gv[s0] * C0;
                alpha = fmaf(gC0, ts, alpha);
                tb = fmaf(gC0, tp, tb);
                float dA1 = __builtin_amdgcn_exp2f(dtv[s1] * an);
                ts = fmaf(dA1, ts, duv[s1] * B1);
                tp *= dA1;
                float gC1 = gv[s1] * C1;
                alpha = fmaf(gC1, ts, alpha);
                tb = fmaf(gC1, tp, tb);
            }
            P[n] = tp; S[n] = ts; beta[n] = tb;
        }
    }
    #pragma unroll
    for (int off = 1; off < 64; off <<= 1) {
        #pragma unroll
        for (int n = 0; n < 8; ++n) {
            float Pp = __shfl_up(P[n], off);
            float Sp = __shfl_up(S[n], off);
            Pp = (lane >= off) ? Pp : 1.f;
            Sp = (lane >= off) ? Sp : 0.f;
            S[n] = fmaf(P[n], Sp, S[n]);
            P[n] *= Pp;
        }
    }
    float gacc = alpha;
    #pragma unroll
    for (int n = 0; n < 8; ++n) {
        float Hs = __shfl_up(S[n], 1);
        float h0 = (lane == 0) ? 0.f : Hs;
        gacc = fmaf(beta[n], h0, gacc);
    }
    #pragma unroll
    for (int off = 1; off < 64; off <<= 1) gacc += __shfl_xor(gacc, off);
    if (lane == 0) part[wv] = gacc;
    __syncthreads();
    if (tid < 2)
        gsum[bd * 512 + (blk & 255) * 2 + tid] = part[tid * 2] + part[tid * 2 + 1];
}

// ---------------------------------------------------------------------------
// Final projections (two wave-cooperative GEMVs).
// ---------------------------------------------------------------------------
__global__ __launch_bounds__(256)
void final_embd(const float* __restrict__ gsum, const float* __restrict__ out_w,
                float* __restrict__ embd)
{
    const int b  = blockIdx.x >> 3;
    const int jg = blockIdx.x & 7;
    const int wv = threadIdx.x >> 6;
    const int lane = threadIdx.x & 63;
    for (int t = 0; t < 16; ++t) {
        int j  = jg * 64 + wv * 16 + t;
        int dd = j >> 8, jj = j & 255;
        const float* wp = out_w + (size_t)(dd * 256 + jj) * 512 + lane * 8;
        const float* gp = gsum + (size_t)(dd * 4 + b) * 512 + lane * 8;
        float4 w0 = *(const float4*)wp;
        float4 w1 = *(const float4*)(wp + 4);
        float4 g0 = *(const float4*)gp;
        float4 g1 = *(const float4*)(gp + 4);
        float s = w0.x * g0.x + w0.y * g0.y + w0.z * g0.z + w0.w * g0.w
                + w1.x * g1.x + w1.y * g1.y + w1.z * g1.z + w1.w * g1.w;
        #pragma unroll
        for (int off = 1; off < 64; off <<= 1) s += __shfl_xor(s, off);
        if (lane == 0) embd[b * 512 + j] = s * (1.0f / 2048.0f);
    }
}

__global__ __launch_bounds__(256)
void final_out(const float* __restrict__ embd, const float* __restrict__ op_w,
               const float* __restrict__ op_b, float* __restrict__ out)
{
    const int b  = blockIdx.x >> 2;
    const int ig = blockIdx.x & 3;
    const int wv = threadIdx.x >> 6;
    const int lane = threadIdx.x & 63;
    for (int t = 0; t < 16; ++t) {
        int i = ig * 64 + wv * 16 + t;
        const float* wp = op_w + (size_t)i * 512 + lane * 8;
        const float* ep = embd + (size_t)b * 512 + lane * 8;
        float4 w0 = *(const float4*)wp;
        float4 w1 = *(const float4*)(wp + 4);
        float4 e0 = *(const float4*)ep;
        float4 e1 = *(const float4*)(ep + 4);
        float s = w0.x * e0.x + w0.y * e0.y + w0.z * e0.z + w0.w * e0.w
                + w1.x * e1.x + w1.y * e1.y + w1.z * e1.z + w1.w * e1.w;
        #pragma unroll
        for (int off = 1; off < 64; off <<= 1) s += __shfl_xor(s, off);
        if (lane == 0) out[b * 256 + i] = s + op_b[i];
    }
}

// ---------------------------------------------------------------------------
extern "C" void kernel_launch(void* const* d_in, const int* in_sizes, int n_in,
                              void* d_out, int out_size, void* d_ws, size_t ws_size,
                              hipStream_t stream)
{
    (void)in_sizes; (void)n_in; (void)out_size; (void)ws_size;
    const float* x       = (const float*)d_in[0];
    const float* ip_w    = (const float*)d_in[1];
    const float* ip_b    = (const float*)d_in[2];
    const float* in_w    = (const float*)d_in[3];
    const float* conv_w  = (const float*)d_in[4];
    const float* conv_b  = (const float*)d_in[5];
    const float* xproj_w = (const float*)d_in[6];
    const float* dt_w    = (const float*)d_in[7];
    const float* dt_b    = (const float*)d_in[8];
    const float* A_log   = (const float*)d_in[9];
    const float* Dp      = (const float*)d_in[10];
    const float* out_w   = (const float*)d_in[11];
    const float* op_w    = (const float*)d_in[12];
    const float* op_b    = (const float*)d_in[13];
    float* out = (float*)d_out;

    // Workspace (53,370,880 B):
    //   xzT   [0,        33554432)  [2][1024][8192] bf16 time-major
    //   uT    [33554432, 50331648)  [2][512][8192]  bf16 (step 5 writes)
    //     ALIASED inside uT region, all dead before conv writes uT:
    //     w2_b  @33554432  [2048][512] bf16 (2 MB)
    //     bias2 @35651584  [2048] fp32 (8 KB)
    //     xb    @35659776  [8192][512] bf16 (8.4 MB)
    //   dbcT  [50331648, 51904512)  [2][48][8192]   bf16 n-major
    //   gsum  [51904512, 51920896)  [8][512]        fp32
    //   wpack [51920896, 53362688)  720896 bf16: ipwT|in_w|xproj_w|dt_w
    //   embd  [53362688, 53370880)  [4][512]        fp32
    char* ws = (char*)d_ws;
    u16*   xzT   = (u16*)(ws + 0);
    u16*   uT    = (u16*)(ws + 33554432);
    u16*   w2_b  = (u16*)(ws + 33554432);
    float* bias2 = (float*)(ws + 35651584);
    u16*   xb    = (u16*)(ws + 35659776);
    u16*   dbcT  = (u16*)(ws + 50331648);
    float* gsum  = (float*)(ws + 51904512);
    u16*   wpk   = (u16*)(ws + 51920896);
    float* embd  = (float*)(ws + 53362688);
    u16*   ipwT_b   = wpk;               // 131072 (ip_w transposed [512][256])
    u16*   inw_b    = wpk + 131072;      // 524288
    u16*   xprojw_b = wpk + 655360;      // 49152
    u16*   dtw_b    = wpk + 704512;      // 16384

    dim3 blk(256);

    // 0) prepack weights (ipwT transposed) + x -> bf16 + bias2 GEMV
    pack_weights<<<dim3(352), blk, 0, stream>>>(ip_w, in_w, xproj_w, dt_w, wpk);
    pack_x<<<dim3(2048), blk, 0, stream>>>(x, xb);
    gemv_bias2<<<dim3(32), blk, 0, stream>>>(in_w, ip_b, bias2);

    // 0b) W2 = in_w @ ip_w  ([2048,512] bf16, row-major)
    gemm64<0, 0, 0><<<dim3(8, 32, 1), blk, 0, stream>>>(
        inw_b, ipwT_b, nullptr, w2_b, 2048, 512, 256, 256, 256, 512, 0, 0, 0, 0);

    // 1+2 fused) xzT[d] = (xb(_flip d) @ W2[d]^T + bias2[d])^T
    gemm_xz<<<dim3(8, 64, 2), blk, 0, stream>>>(xb, w2_b, bias2, xzT);

    // 3) uT = silu(causal_conv(xiT) + cb)   (w2/bias2/xb now dead)
    conv_silu_T<<<dim3(1024), blk, 0, stream>>>(xzT, conv_w, conv_b, uT);

    // 4) dbcT[d] = ((uT[d])^T @ xproj_w[d]^T)^T   [48][8192] n-major
    gemm64<0, 1, 1><<<dim3(1, 128, 2), blk, 0, stream>>>(
        uT, xprojw_b, nullptr, dbcT, 8192, 48, 512, 8192, 512, 8192,
        (size_t)512 * 8192, (size_t)48 * 512, (size_t)48 * 8192, 0);

    // 5) dtT[d] = softplus(dbcT[0:16]^T @ dt_w[d]^T + dt_b[d])^T -> xzT rows 0:512
    gemm64<1, 1, 1><<<dim3(8, 128, 2), blk, 0, stream>>>(
        dbcT, dtw_b, dt_b, xzT, 8192, 512, 16, 8192, 16, 8192,
        (size_t)48 * 8192, (size_t)512 * 16, (size_t)1024 * 8192, 512);

    // 6) single-pass chunked scan + gated mean-pool
    scan_kernel<<<dim3(2048), blk, 0, stream>>>(xzT, uT, dbcT, A_log, Dp, gsum);

    // 7) final projections
    final_embd<<<dim3(32), blk, 0, stream>>>(gsum, out_w, embd);
    final_out<<<dim3(16), blk, 0, stream>>>(embd, op_w, op_b, out);
}

// Round 13
// 274.748 us; speedup vs baseline: 1.0641x; 1.0220x over previous
//
#include <hip/hip_runtime.h>
#include <stdint.h>

// MambaEncoder on MI355X (gfx950).  == R10 structure (best, 264 us) ==
// R12's step-1+2 fusion REVERTED: W2=in_w@ip_w raises K 256->512, +65% MAC,
// +16.5 us measured. R11's BK=64 dbuf REVERTED earlier (+28 us, occupancy).
// ALL inputs and the output are FLOAT32. Intermediates bf16, TIME-MAJOR;
// dbc n-major. Weights prepacked fp32->bf16. CTRANS epilogues via LDS
// transpose. Scan split into 2 dispatches (one per direction) so kernels
// >41 us surface in the top-5 profile slots (diagnostic, cost ~1 launch).

typedef unsigned short u16;
typedef __bf16 bf16x8 __attribute__((ext_vector_type(8)));
typedef float f32x4 __attribute__((ext_vector_type(4)));

#define LOG2E 1.44269504088896f

__device__ __forceinline__ float b2f(u16 h) {
    union { unsigned int u; float f; } c; c.u = ((unsigned int)h) << 16; return c.f;
}
__device__ __forceinline__ u16 f2b(float f) {   // round-to-nearest-even
    union { float f; unsigned int u; } c; c.f = f;
    unsigned int r = c.u + 0x7FFFu + ((c.u >> 16) & 1u);
    return (u16)(r >> 16);
}
__device__ __forceinline__ void unpk2(unsigned int u, float& lo, float& hi) {
    union { unsigned int x; float f; } c0, c1;
    c0.x = u << 16; c1.x = u & 0xffff0000u;
    lo = c0.f; hi = c1.f;
}
__device__ __forceinline__ float silu(float x) {
    return x * __builtin_amdgcn_rcpf(1.f + __builtin_amdgcn_exp2f(-LOG2E * x));
}

// ---------------------------------------------------------------------------
// Weight prepack: fp32 -> bf16 (RNE). Segments:
//   ip_w 131072 | in_w 524288 | xproj_w 49152 | dt_w 16384
// ---------------------------------------------------------------------------
__global__ __launch_bounds__(256)
void pack_weights(const float* __restrict__ s0, const float* __restrict__ s1,
                  const float* __restrict__ s2, const float* __restrict__ s3,
                  u16* __restrict__ dst)
{
    int idx = (blockIdx.x * 256 + threadIdx.x) * 8;
    const float* src; int off;
    if (idx < 131072)      { src = s0; off = idx; }
    else if (idx < 655360) { src = s1; off = idx - 131072; }
    else if (idx < 704512) { src = s2; off = idx - 655360; }
    else                   { src = s3; off = idx - 704512; }
    float4 f0 = *(const float4*)(src + off);
    float4 f1 = *(const float4*)(src + off + 4);
    union { u16 s[8]; uint4 v; } t;
    t.s[0] = f2b(f0.x); t.s[1] = f2b(f0.y); t.s[2] = f2b(f0.z); t.s[3] = f2b(f0.w);
    t.s[4] = f2b(f1.x); t.s[5] = f2b(f1.y); t.s[6] = f2b(f1.z); t.s[7] = f2b(f1.w);
    *(uint4*)(dst + idx) = t.v;
}

// ---------------------------------------------------------------------------
// 128x128 MFMA GEMM: C = A @ W^T + bias. M%128==0, N%128==0, K%32==0.
// W bf16 prepacked. AF32: A fp32. CTRANS: CT[n][m] via LDS transpose.
// ZFLIP: dir-1 time flip on A rows (L=2048).
// ---------------------------------------------------------------------------
template<int AF32, int CTRANS, int ZFLIP>
__global__ __launch_bounds__(256)
void gemm128(const void* __restrict__ Av, const u16* __restrict__ Wb,
             const float* __restrict__ bias, u16* __restrict__ C,
             int M, int N, int K, int lda, int ldw, int ldc,
             size_t azs, size_t wzs, size_t czs)
{
    __shared__ u16 sh[10240];       // As 128x40 | Ws 128x40 ; epilogue reuses
    u16* As = sh;
    u16* Ws = sh + 5120;
    const int z    = blockIdx.z;
    const int flip = ZFLIP ? z : 0;
    Wb += (size_t)z * wzs;
    C  += (size_t)z * czs;
    const u16*   A16 = (const u16*)Av + (AF32 ? 0 : (size_t)z * azs);
    const float* A32 = (const float*)Av + (AF32 ? (size_t)z * azs : 0);

    const int tid  = threadIdx.x;
    const int n0   = blockIdx.x * 128;
    const int m0   = blockIdx.y * 128;
    const int w    = tid >> 6;
    const int lane = tid & 63;
    const int r16  = lane & 15;
    const int q    = lane >> 4;
    const int wm   = (w >> 1) * 64;
    const int wn   = (w & 1) * 64;

    f32x4 acc[4][4];
    #pragma unroll
    for (int i = 0; i < 4; ++i)
        #pragma unroll
        for (int j = 0; j < 4; ++j) acc[i][j] = (f32x4){0.f, 0.f, 0.f, 0.f};

    const int KT = K >> 5;
    for (int kt = 0; kt < KT; ++kt) {
        #pragma unroll
        for (int rr = 0; rr < 2; ++rr) {
            int idx = rr * 256 + tid;
            int row = idx >> 2;
            int col = (kt << 5) + (idx & 3) * 8;
            {   // A
                int m   = m0 + row;
                int src = flip ? ((m & ~2047) | (2047 - (m & 2047))) : m;
                union { u16 s[8]; uint4 v; } t;
                if (AF32) {
                    const float* sp = A32 + (size_t)src * lda + col;
                    float4 f0 = *(const float4*)sp;
                    float4 f1 = *(const float4*)(sp + 4);
                    t.s[0] = f2b(f0.x); t.s[1] = f2b(f0.y);
                    t.s[2] = f2b(f0.z); t.s[3] = f2b(f0.w);
                    t.s[4] = f2b(f1.x); t.s[5] = f2b(f1.y);
                    t.s[6] = f2b(f1.z); t.s[7] = f2b(f1.w);
                } else {
                    t.v = *(const uint4*)(A16 + (size_t)src * lda + col);
                }
                *(uint4*)(&As[row * 40 + (idx & 3) * 8]) = t.v;
            }
            {   // W
                uint4 v = *(const uint4*)(Wb + (size_t)(n0 + row) * ldw + col);
                *(uint4*)(&Ws[row * 40 + (idx & 3) * 8]) = v;
            }
        }
        __syncthreads();
        bf16x8 af[4], wf[4];
        #pragma unroll
        for (int i = 0; i < 4; ++i)
            af[i] = *(const bf16x8*)(&As[(wm + i * 16 + r16) * 40 + q * 8]);
        #pragma unroll
        for (int j = 0; j < 4; ++j)
            wf[j] = *(const bf16x8*)(&Ws[(wn + j * 16 + r16) * 40 + q * 8]);
        #pragma unroll
        for (int i = 0; i < 4; ++i)
            #pragma unroll
            for (int j = 0; j < 4; ++j)
                acc[i][j] = __builtin_amdgcn_mfma_f32_16x16x32_bf16(af[i], wf[j], acc[i][j], 0, 0, 0);
        __syncthreads();
    }
    if (CTRANS) {
        // two n-halves of 64 rows through LDS (stride 132 -> dense stores)
        #pragma unroll
        for (int h = 0; h < 2; ++h) {
            if ((w & 1) == h) {
                #pragma unroll
                for (int j = 0; j < 4; ++j) {
                    float bv = bias ? bias[n0 + wn + j * 16 + r16] : 0.f;
                    #pragma unroll
                    for (int i = 0; i < 4; ++i) {
                        union { u16 s[4]; uint2 v; } pk;
                        #pragma unroll
                        for (int rg = 0; rg < 4; ++rg) pk.s[rg] = f2b(acc[i][j][rg] + bv);
                        *(uint2*)(&sh[(j * 16 + r16) * 132 + wm + i * 16 + q * 4]) = pk.v;
                    }
                }
            }
            __syncthreads();
            int row = tid >> 2, part = tid & 3;
            const u16* sp2 = &sh[row * 132 + part * 32];
            u16* dp = C + (size_t)(n0 + h * 64 + row) * ldc + m0 + part * 32;
            uint4 v0 = *(const uint4*)(sp2);
            uint4 v1 = *(const uint4*)(sp2 + 8);
            uint4 v2 = *(const uint4*)(sp2 + 16);
            uint4 v3 = *(const uint4*)(sp2 + 24);
            ((uint4*)dp)[0] = v0; ((uint4*)dp)[1] = v1;
            ((uint4*)dp)[2] = v2; ((uint4*)dp)[3] = v3;
            __syncthreads();
        }
    } else {
        #pragma unroll
        for (int j = 0; j < 4; ++j) {
            int n = n0 + wn + j * 16 + r16;
            float bv = bias ? bias[n] : 0.f;
            #pragma unroll
            for (int i = 0; i < 4; ++i)
                #pragma unroll
                for (int rg = 0; rg < 4; ++rg) {
                    int m = m0 + wm + i * 16 + q * 4 + rg;
                    C[(size_t)m * ldc + n] = f2b(acc[i][j][rg] + bv);
                }
        }
    }
}

// ---------------------------------------------------------------------------
// 64x64 MFMA GEMM (skinny N/K, steps 4-5). W bf16 prepacked. A bf16.
// ATRANS: A stored [K][M], rows >= K read as 0. CTRANS via LDS transpose.
// ACT: 0 none, 1 softplus.
// ---------------------------------------------------------------------------
template<int ACT, int ATRANS, int CTRANS>
__global__ __launch_bounds__(256)
void gemm64(const u16* __restrict__ A16, const u16* __restrict__ Wb,
            const float* __restrict__ bias, u16* __restrict__ C,
            int M, int N, int K, int lda, int ldw, int ldc,
            size_t azs, size_t wzs, size_t czs, int bzs)
{
    __shared__ u16 sh[5120];
    u16* As = sh;
    u16* Ws = sh + 2560;
    const int z = blockIdx.z;
    Wb += (size_t)z * wzs;
    C  += (size_t)z * czs;
    if (bias) bias += (size_t)z * bzs;
    const u16* A = A16 + (size_t)z * azs;

    const int tid  = threadIdx.x;
    const int n0   = blockIdx.x * 64;
    const int m0   = blockIdx.y * 64;
    const int r    = tid >> 2;
    const int seg  = tid & 3;
    const int w    = tid >> 6;
    const int lane = tid & 63;
    const int r16  = lane & 15;
    const int q    = lane >> 4;

    f32x4 acc[4];
    #pragma unroll
    for (int i = 0; i < 4; ++i) acc[i] = (f32x4){0.f, 0.f, 0.f, 0.f};

    const int KT = (K + 31) >> 5;
    for (int kt = 0; kt < KT; ++kt) {
        const int kk = (kt << 5) + seg * 8;
        if (ATRANS) {
            int k  = tid >> 3;
            int sg = tid & 7;
            int kd = (kt << 5) + k;
            uint4 v = (uint4){0, 0, 0, 0};
            if (kd < K) v = *(const uint4*)(A + (size_t)kd * lda + m0 + sg * 8);
            const u16* vs = (const u16*)&v;
            #pragma unroll
            for (int e = 0; e < 8; ++e) As[(sg * 8 + e) * 40 + k] = vs[e];
        } else {
            const u16* sp = A + (size_t)(m0 + r) * lda;
            union { u16 s[8]; uint4 v; } t;
            if (kk + 8 <= K) {
                t.v = *(const uint4*)(sp + kk);
            } else {
                #pragma unroll
                for (int e = 0; e < 8; ++e)
                    t.s[e] = ((kk + e) < K) ? sp[kk + e] : (u16)0;
            }
            *(uint4*)(&As[r * 40 + seg * 8]) = t.v;
        }
        {
            int n = n0 + r;
            const u16* sp = Wb + (size_t)n * ldw;
            union { u16 s[8]; uint4 v; } t;
            if (n < N && kk + 8 <= K) {
                t.v = *(const uint4*)(sp + kk);
            } else {
                #pragma unroll
                for (int e = 0; e < 8; ++e)
                    t.s[e] = (n < N && (kk + e) < K) ? sp[kk + e] : (u16)0;
            }
            *(uint4*)(&Ws[r * 40 + seg * 8]) = t.v;
        }
        __syncthreads();
        bf16x8 af = *(const bf16x8*)(&As[(w * 16 + r16) * 40 + q * 8]);
        #pragma unroll
        for (int nt = 0; nt < 4; ++nt) {
            bf16x8 wf = *(const bf16x8*)(&Ws[(nt * 16 + r16) * 40 + q * 8]);
            acc[nt] = __builtin_amdgcn_mfma_f32_16x16x32_bf16(af, wf, acc[nt], 0, 0, 0);
        }
        __syncthreads();
    }
    if (CTRANS) {
        #pragma unroll
        for (int nt = 0; nt < 4; ++nt) {
            float bv = bias ? bias[n0 + nt * 16 + r16] : 0.f;
            union { u16 s[4]; uint2 v; } pk;
            #pragma unroll
            for (int rg = 0; rg < 4; ++rg) {
                float v = acc[nt][rg] + bv;
                if (ACT == 1) v = (v > 20.f) ? v : __logf(1.f + __expf(v));
                pk.s[rg] = f2b(v);
            }
            *(uint2*)(&sh[(nt * 16 + r16) * 68 + w * 16 + q * 4]) = pk.v;
        }
        __syncthreads();
        int row = tid >> 2, part = tid & 3;
        if (n0 + row < N) {
            const u16* sp2 = &sh[row * 68 + part * 16];
            u16* dp = C + (size_t)(n0 + row) * ldc + m0 + part * 16;
            uint4 v0 = *(const uint4*)(sp2);
            uint4 v1 = *(const uint4*)(sp2 + 8);
            ((uint4*)dp)[0] = v0; ((uint4*)dp)[1] = v1;
        }
    } else {
        #pragma unroll
        for (int nt = 0; nt < 4; ++nt) {
            int n = n0 + nt * 16 + r16;
            if (n >= N) continue;
            float bv = bias ? bias[n] : 0.f;
            #pragma unroll
            for (int rg = 0; rg < 4; ++rg) {
                int m = m0 + w * 16 + q * 4 + rg;
                float v = acc[nt][rg] + bv;
                if (ACT == 1) v = (v > 20.f) ? v : __logf(1.f + __expf(v));
                C[(size_t)m * ldc + n] = f2b(v);
            }
        }
    }
}

// ---------------------------------------------------------------------------
// Depthwise causal conv (4 taps) + silu, time-major.
// ---------------------------------------------------------------------------
__global__ __launch_bounds__(256)
void conv_silu_T(const u16* __restrict__ xzT, const float* __restrict__ cw,
                 const float* __restrict__ cb, u16* __restrict__ uT)
{
    int g    = blockIdx.x * 256 + threadIdx.x;
    int tile = g & 63;
    int b    = (g >> 6) & 3;
    int ch   = (g >> 8) & 511;
    int d    = g >> 17;
    int l0   = tile * 32;
    const u16* row = xzT + ((size_t)d * 1024 + ch) * 8192 + b * 2048;

    union { u16 s[40]; uint4 v[5]; } wd;
    wd.v[0] = (tile > 0) ? *(const uint4*)(row + l0 - 8) : (uint4){0, 0, 0, 0};
    #pragma unroll
    for (int i = 0; i < 4; ++i) wd.v[1 + i] = *(const uint4*)(row + l0 + i * 8);

    const float* wp = cw + (size_t)(d * 512 + ch) * 4;
    float c0 = wp[0], c1 = wp[1], c2 = wp[2], c3 = wp[3];
    float bias = cb[d * 512 + ch];

    union { u16 s[32]; uint4 v[4]; } o;
    #pragma unroll
    for (int i = 0; i < 32; ++i) {
        float acc = bias + c0 * b2f(wd.s[5 + i]) + c1 * b2f(wd.s[6 + i])
                         + c2 * b2f(wd.s[7 + i]) + c3 * b2f(wd.s[8 + i]);
        o.s[i] = f2b(silu(acc));
    }
    u16* orow = uT + ((size_t)d * 512 + ch) * 8192 + b * 2048 + l0;
    #pragma unroll
    for (int i = 0; i < 4; ++i) ((uint4*)orow)[i] = o.v[i];
}

// ---------------------------------------------------------------------------
// Single-pass chunked associative scan, 8 states/thread (R10 version).
// One dispatch per direction (dsel): grid 1024, bd = dsel*4 + b.
// ---------------------------------------------------------------------------
__global__ __launch_bounds__(256)
void scan_kernel(const u16* __restrict__ xzT, const u16* __restrict__ uT,
                 const u16* __restrict__ dbcT, const float* __restrict__ A_log,
                 const float* __restrict__ Dp, float* __restrict__ gsum, int dsel)
{
    __shared__ float part[4];
    const int tid  = threadIdx.x;
    const int wv   = tid >> 6;
    const int lane = tid & 63;
    const int blk  = blockIdx.x;              // 0..1023
    const int b    = blk >> 8;                // batch
    const int d    = dsel;
    const int bd   = d * 4 + b;
    const int ch   = (blk & 255) * 2 + (wv >> 1);
    const int nh   = (wv & 1) * 8;

    const u16* pdt = xzT + ((size_t)d * 1024 + ch) * 8192 + b * 2048 + lane * 32;
    const u16* pz  = xzT + ((size_t)d * 1024 + 512 + ch) * 8192 + b * 2048 + lane * 32;
    const u16* pu  = uT + ((size_t)d * 512 + ch) * 8192 + b * 2048 + lane * 32;
    const u16* pB  = dbcT + ((size_t)d * 48 + 16 + nh) * 8192 + b * 2048 + lane * 32;
    const u16* pC  = dbcT + ((size_t)d * 48 + 32 + nh) * 8192 + b * 2048 + lane * 32;

    float a[8];
    #pragma unroll
    for (int n = 0; n < 8; ++n)
        a[n] = -LOG2E * __expf(A_log[(d * 512 + ch) * 16 + nh + n]);
    const float DvEff = (wv & 1) ? 0.f : Dp[d * 512 + ch];

    float P[8], S[8], beta[8];
    #pragma unroll
    for (int n = 0; n < 8; ++n) { P[n] = 1.f; S[n] = 0.f; beta[n] = 0.f; }
    float alpha = 0.f;

    #pragma unroll 1
    for (int gq = 0; gq < 4; ++gq) {
        uint4 vdt = *(const uint4*)(pdt + gq * 8);
        uint4 vu  = *(const uint4*)(pu + gq * 8);
        uint4 vz  = *(const uint4*)(pz + gq * 8);
        const u16* ds = (const u16*)&vdt;
        const u16* us = (const u16*)&vu;
        const u16* zs = (const u16*)&vz;
        float dtv[8], duv[8], gv[8];
        #pragma unroll
        for (int s = 0; s < 8; ++s) {
            float dt = b2f(ds[s]), uv = b2f(us[s]), zv = b2f(zs[s]);
            dtv[s] = dt;
            duv[s] = dt * uv;
            float g = silu(zv);
            gv[s] = g;
            alpha = fmaf(g * uv, DvEff, alpha);
        }
        #pragma unroll
        for (int n = 0; n < 8; ++n) {
            uint4 Bq = *(const uint4*)(pB + (size_t)n * 8192 + gq * 8);
            uint4 Cq = *(const uint4*)(pC + (size_t)n * 8192 + gq * 8);
            unsigned int bw[4] = {Bq.x, Bq.y, Bq.z, Bq.w};
            unsigned int cw2[4] = {Cq.x, Cq.y, Cq.z, Cq.w};
            float tp = P[n], ts = S[n], tb = beta[n], an = a[n];
            #pragma unroll
            for (int w2 = 0; w2 < 4; ++w2) {
                float B0, B1, C0, C1;
                unpk2(bw[w2], B0, B1);
                unpk2(cw2[w2], C0, C1);
                int s0 = 2 * w2, s1 = s0 + 1;
                float dA0 = __builtin_amdgcn_exp2f(dtv[s0] * an);
                ts = fmaf(dA0, ts, duv[s0] * B0);
                tp *= dA0;
                float gC0 = gv[s0] * C0;
                alpha = fmaf(gC0, ts, alpha);
                tb = fmaf(gC0, tp, tb);
                float dA1 = __builtin_amdgcn_exp2f(dtv[s1] * an);
                ts = fmaf(dA1, ts, duv[s1] * B1);
                tp *= dA1;
                float gC1 = gv[s1] * C1;
                alpha = fmaf(gC1, ts, alpha);
                tb = fmaf(gC1, tp, tb);
            }
            P[n] = tp; S[n] = ts; beta[n] = tb;
        }
    }
    #pragma unroll
    for (int off = 1; off < 64; off <<= 1) {
        #pragma unroll
        for (int n = 0; n < 8; ++n) {
            float Pp = __shfl_up(P[n], off);
            float Sp = __shfl_up(S[n], off);
            Pp = (lane >= off) ? Pp : 1.f;
            Sp = (lane >= off) ? Sp : 0.f;
            S[n] = fmaf(P[n], Sp, S[n]);
            P[n] *= Pp;
        }
    }
    float gacc = alpha;
    #pragma unroll
    for (int n = 0; n < 8; ++n) {
        float Hs = __shfl_up(S[n], 1);
        float h0 = (lane == 0) ? 0.f : Hs;
        gacc = fmaf(beta[n], h0, gacc);
    }
    #pragma unroll
    for (int off = 1; off < 64; off <<= 1) gacc += __shfl_xor(gacc, off);
    if (lane == 0) part[wv] = gacc;
    __syncthreads();
    if (tid < 2)
        gsum[bd * 512 + (blk & 255) * 2 + tid] = part[tid * 2] + part[tid * 2 + 1];
}

// ---------------------------------------------------------------------------
// Final projections (two wave-cooperative GEMVs).
// ---------------------------------------------------------------------------
__global__ __launch_bounds__(256)
void final_embd(const float* __restrict__ gsum, const float* __restrict__ out_w,
                float* __restrict__ embd)
{
    const int b  = blockIdx.x >> 3;
    const int jg = blockIdx.x & 7;
    const int wv = threadIdx.x >> 6;
    const int lane = threadIdx.x & 63;
    for (int t = 0; t < 16; ++t) {
        int j  = jg * 64 + wv * 16 + t;
        int dd = j >> 8, jj = j & 255;
        const float* wp = out_w + (size_t)(dd * 256 + jj) * 512 + lane * 8;
        const float* gp = gsum + (size_t)(dd * 4 + b) * 512 + lane * 8;
        float4 w0 = *(const float4*)wp;
        float4 w1 = *(const float4*)(wp + 4);
        float4 g0 = *(const float4*)gp;
        float4 g1 = *(const float4*)(gp + 4);
        float s = w0.x * g0.x + w0.y * g0.y + w0.z * g0.z + w0.w * g0.w
                + w1.x * g1.x + w1.y * g1.y + w1.z * g1.z + w1.w * g1.w;
        #pragma unroll
        for (int off = 1; off < 64; off <<= 1) s += __shfl_xor(s, off);
        if (lane == 0) embd[b * 512 + j] = s * (1.0f / 2048.0f);
    }
}

__global__ __launch_bounds__(256)
void final_out(const float* __restrict__ embd, const float* __restrict__ op_w,
               const float* __restrict__ op_b, float* __restrict__ out)
{
    const int b  = blockIdx.x >> 2;
    const int ig = blockIdx.x & 3;
    const int wv = threadIdx.x >> 6;
    const int lane = threadIdx.x & 63;
    for (int t = 0; t < 16; ++t) {
        int i = ig * 64 + wv * 16 + t;
        const float* wp = op_w + (size_t)i * 512 + lane * 8;
        const float* ep = embd + (size_t)b * 512 + lane * 8;
        float4 w0 = *(const float4*)wp;
        float4 w1 = *(const float4*)(wp + 4);
        float4 e0 = *(const float4*)ep;
        float4 e1 = *(const float4*)(ep + 4);
        float s = w0.x * e0.x + w0.y * e0.y + w0.z * e0.z + w0.w * e0.w
                + w1.x * e1.x + w1.y * e1.y + w1.z * e1.z + w1.w * e1.w;
        #pragma unroll
        for (int off = 1; off < 64; off <<= 1) s += __shfl_xor(s, off);
        if (lane == 0) out[b * 256 + i] = s + op_b[i];
    }
}

// ---------------------------------------------------------------------------
extern "C" void kernel_launch(void* const* d_in, const int* in_sizes, int n_in,
                              void* d_out, int out_size, void* d_ws, size_t ws_size,
                              hipStream_t stream)
{
    (void)in_sizes; (void)n_in; (void)out_size; (void)ws_size;
    const float* x       = (const float*)d_in[0];
    const float* ip_w    = (const float*)d_in[1];
    const float* ip_b    = (const float*)d_in[2];
    const float* in_w    = (const float*)d_in[3];
    const float* conv_w  = (const float*)d_in[4];
    const float* conv_b  = (const float*)d_in[5];
    const float* xproj_w = (const float*)d_in[6];
    const float* dt_w    = (const float*)d_in[7];
    const float* dt_b    = (const float*)d_in[8];
    const float* A_log   = (const float*)d_in[9];
    const float* Dp      = (const float*)d_in[10];
    const float* out_w   = (const float*)d_in[11];
    const float* op_w    = (const float*)d_in[12];
    const float* op_b    = (const float*)d_in[13];
    float* out = (float*)d_out;

    // Workspace (53,370,880 B): xzT | uT (hbuf alias) | dbcT | gsum | wpack | embd
    char* ws = (char*)d_ws;
    u16*   xzT  = (u16*)(ws + 0);
    u16*   uT   = (u16*)(ws + 33554432);
    u16*   hbuf = (u16*)(ws + 33554432);
    u16*   dbcT = (u16*)(ws + 50331648);
    float* gsum = (float*)(ws + 51904512);
    u16*   wpk  = (u16*)(ws + 51920896);
    float* embd = (float*)(ws + 53362688);
    u16*   ipw_b    = wpk;               // 131072
    u16*   inw_b    = wpk + 131072;      // 524288
    u16*   xprojw_b = wpk + 655360;      // 49152
    u16*   dtw_b    = wpk + 704512;      // 16384

    dim3 blk(256);

    // 0) prepack weights fp32->bf16
    pack_weights<<<dim3(352), blk, 0, stream>>>(ip_w, in_w, xproj_w, dt_w, wpk);

    // 1) in_proj: hbuf = x @ ip_w^T + ip_b   [8192,256]
    gemm128<1, 0, 0><<<dim3(2, 64, 1), blk, 0, stream>>>(
        x, ipw_b, ip_b, hbuf, 8192, 256, 512, 512, 512, 256, 0, 0, 0);

    // 2) xzT[d] = (hbuf(_flip d) @ in_w[d]^T)^T   [1024][8192], grid.z = dir
    gemm128<0, 1, 1><<<dim3(8, 64, 2), blk, 0, stream>>>(
        hbuf, inw_b, nullptr, xzT, 8192, 1024, 256, 256, 256, 8192,
        0, (size_t)1024 * 256, (size_t)1024 * 8192);

    // 3) uT = silu(causal_conv(xiT) + cb)
    conv_silu_T<<<dim3(1024), blk, 0, stream>>>(xzT, conv_w, conv_b, uT);

    // 4) dbcT[d] = ((uT[d])^T @ xproj_w[d]^T)^T   [48][8192] n-major
    gemm64<0, 1, 1><<<dim3(1, 128, 2), blk, 0, stream>>>(
        uT, xprojw_b, nullptr, dbcT, 8192, 48, 512, 8192, 512, 8192,
        (size_t)512 * 8192, (size_t)48 * 512, (size_t)48 * 8192, 0);

    // 5) dtT[d] = softplus(dbcT[0:16]^T @ dt_w[d]^T + dt_b[d])^T -> xzT rows 0:512
    gemm64<1, 1, 1><<<dim3(8, 128, 2), blk, 0, stream>>>(
        dbcT, dtw_b, dt_b, xzT, 8192, 512, 16, 8192, 16, 8192,
        (size_t)48 * 8192, (size_t)512 * 16, (size_t)1024 * 8192, 512);

    // 6) scan, one dispatch per direction (diagnostic split: surfaces any
    //    kernel >~41 us in the top-5 profile slots)
    scan_kernel<<<dim3(1024), blk, 0, stream>>>(xzT, uT, dbcT, A_log, Dp, gsum, 0);
    scan_kernel<<<dim3(1024), blk, 0, stream>>>(xzT, uT, dbcT, A_log, Dp, gsum, 1);

    // 7) final projections
    final_embd<<<dim3(32), blk, 0, stream>>>(gsum, out_w, embd);
    final_out<<<dim3(16), blk, 0, stream>>>(embd, op_w, op_b, out);
}

// Round 14
// 265.822 us; speedup vs baseline: 1.0998x; 1.0336x over previous
//
#include <hip/hip_runtime.h>
#include <stdint.h>

// MambaEncoder on MI355X (gfx950).  Base = R10 (264 us best).
// R13 scan split REVERTED (+10.5 us). R14: steps 1+2 staged via
// __builtin_amdgcn_global_load_lds width=16 (m97 ladder: 517->874 TF),
// unpadded [128][32] LDS tiles (async dest = wave-uniform base + lane*16;
// padding breaks it). x packed to bf16 once so both big GEMMs use the
// async path. gemm64 (steps 4/5), conv, scan, finals unchanged from R10.

typedef unsigned short u16;
typedef __bf16 bf16x8 __attribute__((ext_vector_type(8)));
typedef float f32x4 __attribute__((ext_vector_type(4)));

#define LOG2E 1.44269504088896f
#define GLOBAL_AS __attribute__((address_space(1)))
#define LDS_AS    __attribute__((address_space(3)))

__device__ __forceinline__ float b2f(u16 h) {
    union { unsigned int u; float f; } c; c.u = ((unsigned int)h) << 16; return c.f;
}
__device__ __forceinline__ u16 f2b(float f) {   // round-to-nearest-even
    union { float f; unsigned int u; } c; c.f = f;
    unsigned int r = c.u + 0x7FFFu + ((c.u >> 16) & 1u);
    return (u16)(r >> 16);
}
__device__ __forceinline__ void unpk2(unsigned int u, float& lo, float& hi) {
    union { unsigned int x; float f; } c0, c1;
    c0.x = u << 16; c1.x = u & 0xffff0000u;
    lo = c0.f; hi = c1.f;
}
__device__ __forceinline__ float silu(float x) {
    return x * __builtin_amdgcn_rcpf(1.f + __builtin_amdgcn_exp2f(-LOG2E * x));
}

// ---------------------------------------------------------------------------
// Weight prepack: fp32 -> bf16 (RNE). Segments:
//   ip_w 131072 | in_w 524288 | xproj_w 49152 | dt_w 16384
// ---------------------------------------------------------------------------
__global__ __launch_bounds__(256)
void pack_weights(const float* __restrict__ s0, const float* __restrict__ s1,
                  const float* __restrict__ s2, const float* __restrict__ s3,
                  u16* __restrict__ dst)
{
    int idx = (blockIdx.x * 256 + threadIdx.x) * 8;
    const float* src; int off;
    if (idx < 131072)      { src = s0; off = idx; }
    else if (idx < 655360) { src = s1; off = idx - 131072; }
    else if (idx < 704512) { src = s2; off = idx - 655360; }
    else                   { src = s3; off = idx - 704512; }
    float4 f0 = *(const float4*)(src + off);
    float4 f1 = *(const float4*)(src + off + 4);
    union { u16 s[8]; uint4 v; } t;
    t.s[0] = f2b(f0.x); t.s[1] = f2b(f0.y); t.s[2] = f2b(f0.z); t.s[3] = f2b(f0.w);
    t.s[4] = f2b(f1.x); t.s[5] = f2b(f1.y); t.s[6] = f2b(f1.z); t.s[7] = f2b(f1.w);
    *(uint4*)(dst + idx) = t.v;
}

// ---------------------------------------------------------------------------
// Pack x fp32 -> bf16 (enables async-LDS staging in gemm128a step 1).
// 4,194,304 elems, grid 2048.
// ---------------------------------------------------------------------------
__global__ __launch_bounds__(256)
void pack_x(const float* __restrict__ x, u16* __restrict__ xb)
{
    int idx = (blockIdx.x * 256 + threadIdx.x) * 8;
    float4 f0 = *(const float4*)(x + idx);
    float4 f1 = *(const float4*)(x + idx + 4);
    union { u16 s[8]; uint4 v; } t;
    t.s[0] = f2b(f0.x); t.s[1] = f2b(f0.y); t.s[2] = f2b(f0.z); t.s[3] = f2b(f0.w);
    t.s[4] = f2b(f1.x); t.s[5] = f2b(f1.y); t.s[6] = f2b(f1.z); t.s[7] = f2b(f1.w);
    *(uint4*)(xb + idx) = t.v;
}

// ---------------------------------------------------------------------------
// 128x128 MFMA GEMM with async global->LDS staging (m97 structure):
// C = A @ W^T + bias. A,W bf16. M%128==0, N%128==0, K%32==0.
// LDS tiles UNPADDED [128][32] u16 (global_load_lds dest = wave-uniform
// base + lane*16; lane i covers bytes [16i,16i+16) of a 16-row chunk).
// Per wave per kt: 2 async A-loads + 2 async W-loads (vs 16 loads +
// 16 ds_writes before). CTRANS: CT[n][m] via LDS-transpose epilogue.
// ZFLIP: dir-1 time flip on A rows (L=2048).
// ---------------------------------------------------------------------------
template<int CTRANS, int ZFLIP>
__global__ __launch_bounds__(256)
void gemm128a(const u16* __restrict__ A, const u16* __restrict__ Wb,
              const float* __restrict__ bias, u16* __restrict__ C,
              int K, int lda, int ldw, int ldc, size_t wzs, size_t czs)
{
    __shared__ u16 sh[8448];        // main: As[0:4096] Ws[4096:8192]; epi 64x132
    u16* As = sh;
    u16* Ws = sh + 4096;
    const int z    = blockIdx.z;
    const int flip = ZFLIP ? z : 0;
    Wb += (size_t)z * wzs;
    C  += (size_t)z * czs;

    const int tid  = threadIdx.x;
    const int n0   = blockIdx.x * 128;
    const int m0   = blockIdx.y * 128;
    const int w    = tid >> 6;
    const int lane = tid & 63;
    const int r16  = lane & 15;
    const int q    = lane >> 4;
    const int wm   = (w >> 1) * 64;
    const int wn   = (w & 1) * 64;
    const int rowi = lane >> 2;       // 0..15 within 16-row chunk
    const int col8 = (lane & 3) * 8;  // 0,8,16,24

    f32x4 acc[4][4];
    #pragma unroll
    for (int i = 0; i < 4; ++i)
        #pragma unroll
        for (int j = 0; j < 4; ++j) acc[i][j] = (f32x4){0.f, 0.f, 0.f, 0.f};

    const int KT = K >> 5;
    for (int kt = 0; kt < KT; ++kt) {
        __syncthreads();              // prior tile fully consumed
        #pragma unroll
        for (int p = 0; p < 2; ++p) {
            int r   = w * 32 + p * 16 + rowi;
            int m   = m0 + r;
            int src = flip ? ((m & ~2047) | (2047 - (m & 2047))) : m;
            const u16* ga = A + (size_t)src * lda + (kt << 5) + col8;
            __builtin_amdgcn_global_load_lds(
                (GLOBAL_AS const void*)ga,
                (LDS_AS void*)(As + (w * 32 + p * 16) * 32), 16, 0, 0);
            const u16* gw = Wb + (size_t)(n0 + r) * ldw + (kt << 5) + col8;
            __builtin_amdgcn_global_load_lds(
                (GLOBAL_AS const void*)gw,
                (LDS_AS void*)(Ws + (w * 32 + p * 16) * 32), 16, 0, 0);
        }
        __syncthreads();              // drains vmcnt (async loads complete)
        bf16x8 af[4], wf[4];
        #pragma unroll
        for (int i = 0; i < 4; ++i)
            af[i] = *(const bf16x8*)(&As[(wm + i * 16 + r16) * 32 + q * 8]);
        #pragma unroll
        for (int j = 0; j < 4; ++j)
            wf[j] = *(const bf16x8*)(&Ws[(wn + j * 16 + r16) * 32 + q * 8]);
        #pragma unroll
        for (int i = 0; i < 4; ++i)
            #pragma unroll
            for (int j = 0; j < 4; ++j)
                acc[i][j] = __builtin_amdgcn_mfma_f32_16x16x32_bf16(af[i], wf[j], acc[i][j], 0, 0, 0);
    }
    __syncthreads();                  // all frag reads done before sh reuse
    if (CTRANS) {
        #pragma unroll
        for (int h = 0; h < 2; ++h) {
            if ((w & 1) == h) {
                #pragma unroll
                for (int j = 0; j < 4; ++j) {
                    float bv = bias ? bias[n0 + wn + j * 16 + r16] : 0.f;
                    #pragma unroll
                    for (int i = 0; i < 4; ++i) {
                        union { u16 s[4]; uint2 v; } pk;
                        #pragma unroll
                        for (int rg = 0; rg < 4; ++rg) pk.s[rg] = f2b(acc[i][j][rg] + bv);
                        *(uint2*)(&sh[(j * 16 + r16) * 132 + wm + i * 16 + q * 4]) = pk.v;
                    }
                }
            }
            __syncthreads();
            int row = tid >> 2, part = tid & 3;
            const u16* sp2 = &sh[row * 132 + part * 32];
            u16* dp = C + (size_t)(n0 + h * 64 + row) * ldc + m0 + part * 32;
            uint4 v0 = *(const uint4*)(sp2);
            uint4 v1 = *(const uint4*)(sp2 + 8);
            uint4 v2 = *(const uint4*)(sp2 + 16);
            uint4 v3 = *(const uint4*)(sp2 + 24);
            ((uint4*)dp)[0] = v0; ((uint4*)dp)[1] = v1;
            ((uint4*)dp)[2] = v2; ((uint4*)dp)[3] = v3;
            __syncthreads();
        }
    } else {
        #pragma unroll
        for (int j = 0; j < 4; ++j) {
            int n = n0 + wn + j * 16 + r16;
            float bv = bias ? bias[n] : 0.f;
            #pragma unroll
            for (int i = 0; i < 4; ++i)
                #pragma unroll
                for (int rg = 0; rg < 4; ++rg) {
                    int m = m0 + wm + i * 16 + q * 4 + rg;
                    C[(size_t)m * ldc + n] = f2b(acc[i][j][rg] + bv);
                }
        }
    }
}

// ---------------------------------------------------------------------------
// 64x64 MFMA GEMM (skinny N/K, steps 4-5). W bf16 prepacked. A bf16.
// ATRANS: A stored [K][M], rows >= K read as 0. CTRANS via LDS transpose.
// ACT: 0 none, 1 softplus.
// ---------------------------------------------------------------------------
template<int ACT, int ATRANS, int CTRANS>
__global__ __launch_bounds__(256)
void gemm64(const u16* __restrict__ A16, const u16* __restrict__ Wb,
            const float* __restrict__ bias, u16* __restrict__ C,
            int M, int N, int K, int lda, int ldw, int ldc,
            size_t azs, size_t wzs, size_t czs, int bzs)
{
    __shared__ u16 sh[5120];
    u16* As = sh;
    u16* Ws = sh + 2560;
    const int z = blockIdx.z;
    Wb += (size_t)z * wzs;
    C  += (size_t)z * czs;
    if (bias) bias += (size_t)z * bzs;
    const u16* A = A16 + (size_t)z * azs;

    const int tid  = threadIdx.x;
    const int n0   = blockIdx.x * 64;
    const int m0   = blockIdx.y * 64;
    const int r    = tid >> 2;
    const int seg  = tid & 3;
    const int w    = tid >> 6;
    const int lane = tid & 63;
    const int r16  = lane & 15;
    const int q    = lane >> 4;

    f32x4 acc[4];
    #pragma unroll
    for (int i = 0; i < 4; ++i) acc[i] = (f32x4){0.f, 0.f, 0.f, 0.f};

    const int KT = (K + 31) >> 5;
    for (int kt = 0; kt < KT; ++kt) {
        const int kk = (kt << 5) + seg * 8;
        if (ATRANS) {
            int k  = tid >> 3;
            int sg = tid & 7;
            int kd = (kt << 5) + k;
            uint4 v = (uint4){0, 0, 0, 0};
            if (kd < K) v = *(const uint4*)(A + (size_t)kd * lda + m0 + sg * 8);
            const u16* vs = (const u16*)&v;
            #pragma unroll
            for (int e = 0; e < 8; ++e) As[(sg * 8 + e) * 40 + k] = vs[e];
        } else {
            const u16* sp = A + (size_t)(m0 + r) * lda;
            union { u16 s[8]; uint4 v; } t;
            if (kk + 8 <= K) {
                t.v = *(const uint4*)(sp + kk);
            } else {
                #pragma unroll
                for (int e = 0; e < 8; ++e)
                    t.s[e] = ((kk + e) < K) ? sp[kk + e] : (u16)0;
            }
            *(uint4*)(&As[r * 40 + seg * 8]) = t.v;
        }
        {
            int n = n0 + r;
            const u16* sp = Wb + (size_t)n * ldw;
            union { u16 s[8]; uint4 v; } t;
            if (n < N && kk + 8 <= K) {
                t.v = *(const uint4*)(sp + kk);
            } else {
                #pragma unroll
                for (int e = 0; e < 8; ++e)
                    t.s[e] = (n < N && (kk + e) < K) ? sp[kk + e] : (u16)0;
            }
            *(uint4*)(&Ws[r * 40 + seg * 8]) = t.v;
        }
        __syncthreads();
        bf16x8 af = *(const bf16x8*)(&As[(w * 16 + r16) * 40 + q * 8]);
        #pragma unroll
        for (int nt = 0; nt < 4; ++nt) {
            bf16x8 wf = *(const bf16x8*)(&Ws[(nt * 16 + r16) * 40 + q * 8]);
            acc[nt] = __builtin_amdgcn_mfma_f32_16x16x32_bf16(af, wf, acc[nt], 0, 0, 0);
        }
        __syncthreads();
    }
    if (CTRANS) {
        #pragma unroll
        for (int nt = 0; nt < 4; ++nt) {
            float bv = bias ? bias[n0 + nt * 16 + r16] : 0.f;
            union { u16 s[4]; uint2 v; } pk;
            #pragma unroll
            for (int rg = 0; rg < 4; ++rg) {
                float v = acc[nt][rg] + bv;
                if (ACT == 1) v = (v > 20.f) ? v : __logf(1.f + __expf(v));
                pk.s[rg] = f2b(v);
            }
            *(uint2*)(&sh[(nt * 16 + r16) * 68 + w * 16 + q * 4]) = pk.v;
        }
        __syncthreads();
        int row = tid >> 2, part = tid & 3;
        if (n0 + row < N) {
            const u16* sp2 = &sh[row * 68 + part * 16];
            u16* dp = C + (size_t)(n0 + row) * ldc + m0 + part * 16;
            uint4 v0 = *(const uint4*)(sp2);
            uint4 v1 = *(const uint4*)(sp2 + 8);
            ((uint4*)dp)[0] = v0; ((uint4*)dp)[1] = v1;
        }
    } else {
        #pragma unroll
        for (int nt = 0; nt < 4; ++nt) {
            int n = n0 + nt * 16 + r16;
            if (n >= N) continue;
            float bv = bias ? bias[n] : 0.f;
            #pragma unroll
            for (int rg = 0; rg < 4; ++rg) {
                int m = m0 + w * 16 + q * 4 + rg;
                float v = acc[nt][rg] + bv;
                if (ACT == 1) v = (v > 20.f) ? v : __logf(1.f + __expf(v));
                C[(size_t)m * ldc + n] = f2b(v);
            }
        }
    }
}

// ---------------------------------------------------------------------------
// Depthwise causal conv (4 taps) + silu, time-major.
// ---------------------------------------------------------------------------
__global__ __launch_bounds__(256)
void conv_silu_T(const u16* __restrict__ xzT, const float* __restrict__ cw,
                 const float* __restrict__ cb, u16* __restrict__ uT)
{
    int g    = blockIdx.x * 256 + threadIdx.x;
    int tile = g & 63;
    int b    = (g >> 6) & 3;
    int ch   = (g >> 8) & 511;
    int d    = g >> 17;
    int l0   = tile * 32;
    const u16* row = xzT + ((size_t)d * 1024 + ch) * 8192 + b * 2048;

    union { u16 s[40]; uint4 v[5]; } wd;
    wd.v[0] = (tile > 0) ? *(const uint4*)(row + l0 - 8) : (uint4){0, 0, 0, 0};
    #pragma unroll
    for (int i = 0; i < 4; ++i) wd.v[1 + i] = *(const uint4*)(row + l0 + i * 8);

    const float* wp = cw + (size_t)(d * 512 + ch) * 4;
    float c0 = wp[0], c1 = wp[1], c2 = wp[2], c3 = wp[3];
    float bias = cb[d * 512 + ch];

    union { u16 s[32]; uint4 v[4]; } o;
    #pragma unroll
    for (int i = 0; i < 32; ++i) {
        float acc = bias + c0 * b2f(wd.s[5 + i]) + c1 * b2f(wd.s[6 + i])
                         + c2 * b2f(wd.s[7 + i]) + c3 * b2f(wd.s[8 + i]);
        o.s[i] = f2b(silu(acc));
    }
    u16* orow = uT + ((size_t)d * 512 + ch) * 8192 + b * 2048 + l0;
    #pragma unroll
    for (int i = 0; i < 4; ++i) ((uint4*)orow)[i] = o.v[i];
}

// ---------------------------------------------------------------------------
// Single-pass chunked associative scan, 8 states/thread (R10 version,
// single dispatch — R13 split cost +10.5 us).
// ---------------------------------------------------------------------------
__global__ __launch_bounds__(256)
void scan_kernel(const u16* __restrict__ xzT, const u16* __restrict__ uT,
                 const u16* __restrict__ dbcT, const float* __restrict__ A_log,
                 const float* __restrict__ Dp, float* __restrict__ gsum)
{
    __shared__ float part[4];
    const int tid  = threadIdx.x;
    const int wv   = tid >> 6;
    const int lane = tid & 63;
    const int blk  = blockIdx.x;              // 0..2047
    const int bd   = blk >> 8;
    const int d    = bd >> 2, b = bd & 3;
    const int ch   = (blk & 255) * 2 + (wv >> 1);
    const int nh   = (wv & 1) * 8;

    const u16* pdt = xzT + ((size_t)d * 1024 + ch) * 8192 + b * 2048 + lane * 32;
    const u16* pz  = xzT + ((size_t)d * 1024 + 512 + ch) * 8192 + b * 2048 + lane * 32;
    const u16* pu  = uT + ((size_t)d * 512 + ch) * 8192 + b * 2048 + lane * 32;
    const u16* pB  = dbcT + ((size_t)d * 48 + 16 + nh) * 8192 + b * 2048 + lane * 32;
    const u16* pC  = dbcT + ((size_t)d * 48 + 32 + nh) * 8192 + b * 2048 + lane * 32;

    float a[8];
    #pragma unroll
    for (int n = 0; n < 8; ++n)
        a[n] = -LOG2E * __expf(A_log[(d * 512 + ch) * 16 + nh + n]);
    const float DvEff = (wv & 1) ? 0.f : Dp[d * 512 + ch];

    float P[8], S[8], beta[8];
    #pragma unroll
    for (int n = 0; n < 8; ++n) { P[n] = 1.f; S[n] = 0.f; beta[n] = 0.f; }
    float alpha = 0.f;

    #pragma unroll 1
    for (int gq = 0; gq < 4; ++gq) {
        uint4 vdt = *(const uint4*)(pdt + gq * 8);
        uint4 vu  = *(const uint4*)(pu + gq * 8);
        uint4 vz  = *(const uint4*)(pz + gq * 8);
        const u16* ds = (const u16*)&vdt;
        const u16* us = (const u16*)&vu;
        const u16* zs = (const u16*)&vz;
        float dtv[8], duv[8], gv[8];
        #pragma unroll
        for (int s = 0; s < 8; ++s) {
            float dt = b2f(ds[s]), uv = b2f(us[s]), zv = b2f(zs[s]);
            dtv[s] = dt;
            duv[s] = dt * uv;
            float g = silu(zv);
            gv[s] = g;
            alpha = fmaf(g * uv, DvEff, alpha);
        }
        #pragma unroll
        for (int n = 0; n < 8; ++n) {
            uint4 Bq = *(const uint4*)(pB + (size_t)n * 8192 + gq * 8);
            uint4 Cq = *(const uint4*)(pC + (size_t)n * 8192 + gq * 8);
            unsigned int bw[4] = {Bq.x, Bq.y, Bq.z, Bq.w};
            unsigned int cw2[4] = {Cq.x, Cq.y, Cq.z, Cq.w};
            float tp = P[n], ts = S[n], tb = beta[n], an = a[n];
            #pragma unroll
            for (int w2 = 0; w2 < 4; ++w2) {
                float B0, B1, C0, C1;
                unpk2(bw[w2], B0, B1);
                unpk2(cw2[w2], C0, C1);
                int s0 = 2 * w2, s1 = s0 + 1;
                float dA0 = __builtin_amdgcn_exp2f(dtv[s0] * an);
                ts = fmaf(dA0, ts, duv[s0] * B0);
                tp *= dA0;
                float gC0 = gv[s0] * C0;
                alpha = fmaf(gC0, ts, alpha);
                tb = fmaf(gC0, tp, tb);
                float dA1 = __builtin_amdgcn_exp2f(dtv[s1] * an);
                ts = fmaf(dA1, ts, duv[s1] * B1);
                tp *= dA1;
                float gC1 = gv[s1] * C1;
                alpha = fmaf(gC1, ts, alpha);
                tb = fmaf(gC1, tp, tb);
            }
            P[n] = tp; S[n] = ts; beta[n] = tb;
        }
    }
    #pragma unroll
    for (int off = 1; off < 64; off <<= 1) {
        #pragma unroll
        for (int n = 0; n < 8; ++n) {
            float Pp = __shfl_up(P[n], off);
            float Sp = __shfl_up(S[n], off);
            Pp = (lane >= off) ? Pp : 1.f;
            Sp = (lane >= off) ? Sp : 0.f;
            S[n] = fmaf(P[n], Sp, S[n]);
            P[n] *= Pp;
        }
    }
    float gacc = alpha;
    #pragma unroll
    for (int n = 0; n < 8; ++n) {
        float Hs = __shfl_up(S[n], 1);
        float h0 = (lane == 0) ? 0.f : Hs;
        gacc = fmaf(beta[n], h0, gacc);
    }
    #pragma unroll
    for (int off = 1; off < 64; off <<= 1) gacc += __shfl_xor(gacc, off);
    if (lane == 0) part[wv] = gacc;
    __syncthreads();
    if (tid < 2)
        gsum[bd * 512 + (blk & 255) * 2 + tid] = part[tid * 2] + part[tid * 2 + 1];
}

// ---------------------------------------------------------------------------
// Final projections (two wave-cooperative GEMVs).
// ---------------------------------------------------------------------------
__global__ __launch_bounds__(256)
void final_embd(const float* __restrict__ gsum, const float* __restrict__ out_w,
                float* __restrict__ embd)
{
    const int b  = blockIdx.x >> 3;
    const int jg = blockIdx.x & 7;
    const int wv = threadIdx.x >> 6;
    const int lane = threadIdx.x & 63;
    for (int t = 0; t < 16; ++t) {
        int j  = jg * 64 + wv * 16 + t;
        int dd = j >> 8, jj = j & 255;
        const float* wp = out_w + (size_t)(dd * 256 + jj) * 512 + lane * 8;
        const float* gp = gsum + (size_t)(dd * 4 + b) * 512 + lane * 8;
        float4 w0 = *(const float4*)wp;
        float4 w1 = *(const float4*)(wp + 4);
        float4 g0 = *(const float4*)gp;
        float4 g1 = *(const float4*)(gp + 4);
        float s = w0.x * g0.x + w0.y * g0.y + w0.z * g0.z + w0.w * g0.w
                + w1.x * g1.x + w1.y * g1.y + w1.z * g1.z + w1.w * g1.w;
        #pragma unroll
        for (int off = 1; off < 64; off <<= 1) s += __shfl_xor(s, off);
        if (lane == 0) embd[b * 512 + j] = s * (1.0f / 2048.0f);
    }
}

__global__ __launch_bounds__(256)
void final_out(const float* __restrict__ embd, const float* __restrict__ op_w,
               const float* __restrict__ op_b, float* __restrict__ out)
{
    const int b  = blockIdx.x >> 2;
    const int ig = blockIdx.x & 3;
    const int wv = threadIdx.x >> 6;
    const int lane = threadIdx.x & 63;
    for (int t = 0; t < 16; ++t) {
        int i = ig * 64 + wv * 16 + t;
        const float* wp = op_w + (size_t)i * 512 + lane * 8;
        const float* ep = embd + (size_t)b * 512 + lane * 8;
        float4 w0 = *(const float4*)wp;
        float4 w1 = *(const float4*)(wp + 4);
        float4 e0 = *(const float4*)ep;
        float4 e1 = *(const float4*)(ep + 4);
        float s = w0.x * e0.x + w0.y * e0.y + w0.z * e0.z + w0.w * e0.w
                + w1.x * e1.x + w1.y * e1.y + w1.z * e1.z + w1.w * e1.w;
        #pragma unroll
        for (int off = 1; off < 64; off <<= 1) s += __shfl_xor(s, off);
        if (lane == 0) out[b * 256 + i] = s + op_b[i];
    }
}

// ---------------------------------------------------------------------------
extern "C" void kernel_launch(void* const* d_in, const int* in_sizes, int n_in,
                              void* d_out, int out_size, void* d_ws, size_t ws_size,
                              hipStream_t stream)
{
    (void)in_sizes; (void)n_in; (void)out_size; (void)ws_size;
    const float* x       = (const float*)d_in[0];
    const float* ip_w    = (const float*)d_in[1];
    const float* ip_b    = (const float*)d_in[2];
    const float* in_w    = (const float*)d_in[3];
    const float* conv_w  = (const float*)d_in[4];
    const float* conv_b  = (const float*)d_in[5];
    const float* xproj_w = (const float*)d_in[6];
    const float* dt_w    = (const float*)d_in[7];
    const float* dt_b    = (const float*)d_in[8];
    const float* A_log   = (const float*)d_in[9];
    const float* Dp      = (const float*)d_in[10];
    const float* out_w   = (const float*)d_in[11];
    const float* op_w    = (const float*)d_in[12];
    const float* op_b    = (const float*)d_in[13];
    float* out = (float*)d_out;

    // Workspace (53,370,880 B):
    //   xzT   [0,        33554432)  [2][1024][8192] bf16 time-major
    //   uT    [33554432, 50331648)  [2][512][8192]  bf16 (conv writes)
    //     ALIASED inside uT region (dead before conv):
    //     xb    @33554432  [8192][512] bf16 (8.4 MB)
    //     hbuf  @41943040  [8192][256] bf16 (4.2 MB)
    //   dbcT  [50331648, 51904512)  [2][48][8192]   bf16 n-major
    //   gsum  [51904512, 51920896)  [8][512]        fp32
    //   wpack [51920896, 53362688)  720896 bf16: ip_w|in_w|xproj_w|dt_w
    //   embd  [53362688, 53370880)  [4][512]        fp32
    char* ws = (char*)d_ws;
    u16*   xzT  = (u16*)(ws + 0);
    u16*   uT   = (u16*)(ws + 33554432);
    u16*   xb   = (u16*)(ws + 33554432);
    u16*   hbuf = (u16*)(ws + 41943040);
    u16*   dbcT = (u16*)(ws + 50331648);
    float* gsum = (float*)(ws + 51904512);
    u16*   wpk  = (u16*)(ws + 51920896);
    float* embd = (float*)(ws + 53362688);
    u16*   ipw_b    = wpk;               // 131072
    u16*   inw_b    = wpk + 131072;      // 524288
    u16*   xprojw_b = wpk + 655360;      // 49152
    u16*   dtw_b    = wpk + 704512;      // 16384

    dim3 blk(256);

    // 0) prepack weights + x -> bf16
    pack_weights<<<dim3(352), blk, 0, stream>>>(ip_w, in_w, xproj_w, dt_w, wpk);
    pack_x<<<dim3(2048), blk, 0, stream>>>(x, xb);

    // 1) in_proj: hbuf = xb @ ip_w^T + ip_b   [8192,256], async-LDS staging
    gemm128a<0, 0><<<dim3(2, 64, 1), blk, 0, stream>>>(
        xb, ipw_b, ip_b, hbuf, 512, 512, 512, 256, 0, 0);

    // 2) xzT[d] = (hbuf(_flip d) @ in_w[d]^T)^T   [1024][8192], grid.z = dir
    gemm128a<1, 1><<<dim3(8, 64, 2), blk, 0, stream>>>(
        hbuf, inw_b, nullptr, xzT, 256, 256, 256, 8192,
        (size_t)1024 * 256, (size_t)1024 * 8192);

    // 3) uT = silu(causal_conv(xiT) + cb)   (xb/hbuf now dead)
    conv_silu_T<<<dim3(1024), blk, 0, stream>>>(xzT, conv_w, conv_b, uT);

    // 4) dbcT[d] = ((uT[d])^T @ xproj_w[d]^T)^T   [48][8192] n-major
    gemm64<0, 1, 1><<<dim3(1, 128, 2), blk, 0, stream>>>(
        uT, xprojw_b, nullptr, dbcT, 8192, 48, 512, 8192, 512, 8192,
        (size_t)512 * 8192, (size_t)48 * 512, (size_t)48 * 8192, 0);

    // 5) dtT[d] = softplus(dbcT[0:16]^T @ dt_w[d]^T + dt_b[d])^T -> xzT rows 0:512
    gemm64<1, 1, 1><<<dim3(8, 128, 2), blk, 0, stream>>>(
        dbcT, dtw_b, dt_b, xzT, 8192, 512, 16, 8192, 16, 8192,
        (size_t)48 * 8192, (size_t)512 * 16, (size_t)1024 * 8192, 512);

    // 6) single-pass chunked scan + gated mean-pool
    scan_kernel<<<dim3(2048), blk, 0, stream>>>(xzT, uT, dbcT, A_log, Dp, gsum);

    // 7) final projections
    final_embd<<<dim3(32), blk, 0, stream>>>(gsum, out_w, embd);
    final_out<<<dim3(16), blk, 0, stream>>>(embd, op_w, op_b, out);
}